// Round 1
// baseline (362.660 us; speedup 1.0000x reference)
//
#include <hip/hip_runtime.h>
#include <hip/hip_bf16.h>
#include <math.h>

#define B_DIM 64
#define T_DIM 512
#define E_DIM 512   // K = V = 512 too

typedef __bf16 bf16_t;
typedef bf16_t bf16x8 __attribute__((ext_vector_type(8)));
typedef float  f32x4  __attribute__((ext_vector_type(4)));

typedef unsigned char __attribute__((address_space(1))) uc_g;
typedef unsigned char __attribute__((address_space(3))) uc_l;

__device__ __forceinline__ void gl_lds16(const void* g, void* l) {
  __builtin_amdgcn_global_load_lds((const uc_g*)g, (uc_l*)l, 16, 0, 0);
}

// ---------------- f32 -> bf16 convert (vectorized, 8 elems/thread) ----------------
__global__ __launch_bounds__(256) void cvtx_kernel(const float* __restrict__ x,
                                                   bf16_t* __restrict__ xb) {
  const size_t t = (size_t)blockIdx.x * 256 + threadIdx.x;
  const float4 a = ((const float4*)x)[t * 2];
  const float4 b = ((const float4*)x)[t * 2 + 1];
  bf16x8 o;
  o[0] = (bf16_t)a.x; o[1] = (bf16_t)a.y; o[2] = (bf16_t)a.z; o[3] = (bf16_t)a.w;
  o[4] = (bf16_t)b.x; o[5] = (bf16_t)b.y; o[6] = (bf16_t)b.z; o[7] = (bf16_t)b.w;
  *(bf16x8*)(xb + t * 8) = o;
}

// ---------------- W (E x N, f32) -> WT (N x E, bf16); z selects which weight ------
__global__ __launch_bounds__(256) void wtr_kernel(const float* __restrict__ W0,
                                                  const float* __restrict__ W1,
                                                  const float* __restrict__ W2,
                                                  bf16_t* __restrict__ O0,
                                                  bf16_t* __restrict__ O1,
                                                  bf16_t* __restrict__ O2) {
  const float* W = blockIdx.z == 0 ? W0 : (blockIdx.z == 1 ? W1 : W2);
  bf16_t* O = blockIdx.z == 0 ? O0 : (blockIdx.z == 1 ? O1 : O2);
  __shared__ float tile[32][33];
  const int tx = threadIdx.x, ty = threadIdx.y;       // (32,8)
  const int r0 = blockIdx.y * 32, c0 = blockIdx.x * 32;
#pragma unroll
  for (int i = 0; i < 4; ++i)
    tile[ty + i * 8][tx] = W[(size_t)(r0 + ty + i * 8) * E_DIM + c0 + tx];
  __syncthreads();
#pragma unroll
  for (int i = 0; i < 4; ++i)
    O[(size_t)(c0 + ty + i * 8) * E_DIM + r0 + tx] = (bf16_t)tile[tx][ty + i * 8];
}

// ---------------- per-batch bf16 transpose: v[T][V] -> vT[V][T] -------------------
__global__ __launch_bounds__(512) void vtr_kernel(const bf16_t* __restrict__ Vb,
                                                  bf16_t* __restrict__ VT) {
  const int b = blockIdx.z;
  __shared__ bf16_t tile[64][65];
  const int tx = threadIdx.x, ty = threadIdx.y;       // (64,8)
  const bf16_t* src = Vb + (size_t)b * T_DIM * T_DIM;
  bf16_t* dst = VT + (size_t)b * T_DIM * T_DIM;
  const int r0 = blockIdx.y * 64, c0 = blockIdx.x * 64;
#pragma unroll
  for (int i = 0; i < 8; ++i)
    tile[ty + i * 8][tx] = src[(size_t)(r0 + ty + i * 8) * T_DIM + c0 + tx];
  __syncthreads();
#pragma unroll
  for (int i = 0; i < 8; ++i)
    dst[(size_t)(c0 + ty + i * 8) * T_DIM + r0 + tx] = tile[tx][ty + i * 8];
}

// ---------------- NT bf16 MFMA GEMM, 128x128 tile, BK=64, 4 waves -----------------
// C[m][n] = sum_k A[m][k] * Bt[n][k]   (A: M x K row-major, Bt: N x K row-major)
// EPI 0: += bias[n], store bf16      (projections)
// EPI 1: *= scale, mask col>row -> -1e30, store f32 (scores; skip bn>bm blocks)
// EPI 2: store f32, causal K-trunc Kend=(bm+1)*128   (PV)
template <int EPI>
__global__ __launch_bounds__(256)
void gemm_nt(const bf16_t* __restrict__ A, const bf16_t* __restrict__ Bt,
             void* __restrict__ Cv, const float* __restrict__ bias,
             int M, int N, int K, long sA, long sB, long sC, float scale) {
  __shared__ bf16_t lA[128 * 64];
  __shared__ bf16_t lB[128 * 64];
  const int bz = blockIdx.z;
  const int bm = blockIdx.x, bn = blockIdx.y;
  const int tid = threadIdx.x;
  const int wid = tid >> 6, lane = tid & 63;
  const int wr = wid >> 1, wc = wid & 1;
  const int l15 = lane & 15, lk = lane >> 4;

  const long crow0 = (long)bm * 128 + wr * 64 + lk * 4;
  const int ccol0 = bn * 128 + wc * 64 + l15;

  if (EPI == 1 && bn > bm) {  // fully masked score tile: skip GEMM
    float* C = (float*)Cv + (long)bz * sC;
#pragma unroll
    for (int m = 0; m < 4; ++m)
#pragma unroll
      for (int n = 0; n < 4; ++n)
#pragma unroll
        for (int r = 0; r < 4; ++r)
          C[(crow0 + m * 16 + r) * (long)N + ccol0 + n * 16] = -1e30f;
    return;
  }

  const bf16_t* Ab = A + (long)bz * sA;
  const bf16_t* Bb = Bt + (long)bz * sB;

  f32x4 acc[4][4] = {};

  const int srow = tid >> 3;        // 0..31 within a 32-row staging chunk
  const int scol = (tid & 7) * 8;   // 0..56
  const bf16_t* gA = Ab + (long)(bm * 128 + srow) * K + scol;
  const bf16_t* gB = Bb + (long)(bn * 128 + srow) * K + scol;
  const int lbase = wid * 512;      // wave-uniform LDS element base

  const int Kend = (EPI == 2) ? (bm + 1) * 128 : K;

  for (int k0 = 0; k0 < Kend; k0 += 64) {
#pragma unroll
    for (int c = 0; c < 4; ++c) {
      gl_lds16(gA + (long)(c * 32) * K + k0, lA + c * 2048 + lbase);
      gl_lds16(gB + (long)(c * 32) * K + k0, lB + c * 2048 + lbase);
    }
    __syncthreads();
#pragma unroll
    for (int ks = 0; ks < 2; ++ks) {
      bf16x8 af[4], bfr[4];
#pragma unroll
      for (int m = 0; m < 4; ++m)
        af[m] = *(const bf16x8*)&lA[(wr * 64 + m * 16 + l15) * 64 + ks * 32 + lk * 8];
#pragma unroll
      for (int n = 0; n < 4; ++n)
        bfr[n] = *(const bf16x8*)&lB[(wc * 64 + n * 16 + l15) * 64 + ks * 32 + lk * 8];
#pragma unroll
      for (int m = 0; m < 4; ++m)
#pragma unroll
        for (int n = 0; n < 4; ++n)
          acc[m][n] = __builtin_amdgcn_mfma_f32_16x16x32_bf16(af[m], bfr[n], acc[m][n], 0, 0, 0);
    }
    __syncthreads();
  }

  if constexpr (EPI == 0) {
    bf16_t* C = (bf16_t*)Cv + (long)bz * sC;
#pragma unroll
    for (int m = 0; m < 4; ++m)
#pragma unroll
      for (int n = 0; n < 4; ++n) {
        const int col = ccol0 + n * 16;
        const float bv = bias[col];
#pragma unroll
        for (int r = 0; r < 4; ++r)
          C[(crow0 + m * 16 + r) * (long)N + col] = (bf16_t)(acc[m][n][r] + bv);
      }
  } else if constexpr (EPI == 1) {
    float* C = (float*)Cv + (long)bz * sC;
#pragma unroll
    for (int m = 0; m < 4; ++m)
#pragma unroll
      for (int n = 0; n < 4; ++n) {
        const int col = ccol0 + n * 16;
#pragma unroll
        for (int r = 0; r < 4; ++r) {
          const long row = crow0 + m * 16 + r;
          float v = acc[m][n][r] * scale;
          if (col > row) v = -1e30f;   // causal: mask s > t
          C[row * (long)N + col] = v;
        }
      }
  } else {
    float* C = (float*)Cv + (long)bz * sC;
#pragma unroll
    for (int m = 0; m < 4; ++m)
#pragma unroll
      for (int n = 0; n < 4; ++n) {
        const int col = ccol0 + n * 16;
#pragma unroll
        for (int r = 0; r < 4; ++r)
          C[(crow0 + m * 16 + r) * (long)N + col] = acc[m][n][r];
      }
  }
}

// ---------------- column softmax over t (axis=1) per (b, s) -----------------------
// S: f32 [B][T][T] (pre-scaled, masked to -1e30). P: bf16 [B][T][T].
__global__ __launch_bounds__(256) void col_softmax(const float* __restrict__ S,
                                                   bf16_t* __restrict__ P) {
  const int b = blockIdx.y;
  const int tx = threadIdx.x;           // 0..63 -> column s
  const int ty = threadIdx.y;           // 0..3  -> t-chunk
  const int s = blockIdx.x * 64 + tx;
  const float* Sb = S + (size_t)b * T_DIM * T_DIM + s;
  bf16_t* Pb = P + (size_t)b * T_DIM * T_DIM + s;
  const int t0 = ty * 128;
  __shared__ float red[4][64];

  float mx = -3.0e38f;
#pragma unroll 8
  for (int i = 0; i < 128; ++i)
    mx = fmaxf(mx, Sb[(size_t)(t0 + i) * T_DIM]);
  red[ty][tx] = mx;
  __syncthreads();
  mx = fmaxf(fmaxf(red[0][tx], red[1][tx]), fmaxf(red[2][tx], red[3][tx]));
  __syncthreads();

  float d = 0.f;
#pragma unroll 8
  for (int i = 0; i < 128; ++i)
    d += __expf(Sb[(size_t)(t0 + i) * T_DIM] - mx);
  red[ty][tx] = d;
  __syncthreads();
  d = red[0][tx] + red[1][tx] + red[2][tx] + red[3][tx];
  const float inv = 1.f / d;

#pragma unroll 8
  for (int i = 0; i < 128; ++i)
    Pb[(size_t)(t0 + i) * T_DIM] = (bf16_t)(__expf(Sb[(size_t)(t0 + i) * T_DIM] - mx) * inv);
}

// ----------------------------------------------------------------------------------
extern "C" void kernel_launch(void* const* d_in, const int* in_sizes, int n_in,
                              void* d_out, int out_size, void* d_ws, size_t ws_size,
                              hipStream_t stream) {
  const float* x  = (const float*)d_in[0];
  const float* Wq = (const float*)d_in[1];
  const float* bq = (const float*)d_in[2];
  const float* Wk = (const float*)d_in[3];
  const float* bk = (const float*)d_in[4];
  const float* Wv = (const float*)d_in[5];
  const float* bv = (const float*)d_in[6];
  float* out = (float*)d_out;

  char* ws = (char*)d_ws;
  const size_t SZ = (size_t)B_DIM * T_DIM * E_DIM * 2;  // 33,554,432 B per bf16 tensor
  bf16_t* xb  = (bf16_t*)(ws);                // dead after projections
  bf16_t* vb  = (bf16_t*)(ws + SZ);           // dead after vtr
  bf16_t* qb  = (bf16_t*)(ws + 2 * SZ);
  bf16_t* kb  = (bf16_t*)(ws + 3 * SZ);
  bf16_t* vT  = (bf16_t*)(ws + 4 * SZ);
  bf16_t* P   = (bf16_t*)(ws + 5 * SZ);
  bf16_t* WqT = (bf16_t*)(ws + 6 * SZ);
  bf16_t* WkT = (bf16_t*)(ws + 6 * SZ + 524288);
  bf16_t* WvT = (bf16_t*)(ws + 6 * SZ + 2 * 524288);
  float*  S   = (float*)(ws);                 // 67 MB, overlays xb+vb (both dead)

  const int M = B_DIM * T_DIM;                // 32768
  const long bstr = (long)T_DIM * T_DIM;      // 262144 per-batch stride
  const float scale = 1.0f / sqrtf((float)E_DIM);

  // 1. x -> bf16
  cvtx_kernel<<<dim3(8192), dim3(256), 0, stream>>>(x, xb);
  // 2. weight transposes (f32 -> bf16, N x E)
  wtr_kernel<<<dim3(16, 16, 3), dim3(32, 8), 0, stream>>>(Wq, Wk, Wv, WqT, WkT, WvT);
  // 3. projections
  gemm_nt<0><<<dim3(256, 4, 1), dim3(256), 0, stream>>>(xb, WqT, qb, bq, M, 512, 512, 0, 0, 0, 0.f);
  gemm_nt<0><<<dim3(256, 4, 1), dim3(256), 0, stream>>>(xb, WkT, kb, bk, M, 512, 512, 0, 0, 0, 0.f);
  gemm_nt<0><<<dim3(256, 4, 1), dim3(256), 0, stream>>>(xb, WvT, vb, bv, M, 512, 512, 0, 0, 0, 0.f);
  // 4. v -> vT per batch
  vtr_kernel<<<dim3(8, 8, B_DIM), dim3(64, 8), 0, stream>>>(vb, vT);
  // 5. scores = q k^T * scale, causal mask (writes S over dead xb+vb)
  gemm_nt<1><<<dim3(4, 4, B_DIM), dim3(256), 0, stream>>>(qb, kb, S, nullptr, 512, 512, 512,
                                                          bstr, bstr, bstr, scale);
  // 6. column softmax (axis = t) -> bf16 P
  col_softmax<<<dim3(8, B_DIM), dim3(64, 4), 0, stream>>>(S, P);
  // 7. out = P @ v   (NT with vT), causal K-truncation
  gemm_nt<2><<<dim3(4, 4, B_DIM), dim3(256), 0, stream>>>(P, vT, out, nullptr, 512, 512, 512,
                                                          bstr, bstr, bstr, 1.f);
}

// Round 2
// 304.613 us; speedup vs baseline: 1.1906x; 1.1906x over previous
//
#include <hip/hip_runtime.h>
#include <hip/hip_bf16.h>
#include <math.h>

#define B_DIM 64
#define T_DIM 512
#define E_DIM 512   // K = V = 512 too

typedef __bf16 bf16_t;
typedef bf16_t bf16x8 __attribute__((ext_vector_type(8)));
typedef float  f32x4  __attribute__((ext_vector_type(4)));

typedef unsigned char __attribute__((address_space(1))) uc_g;
typedef unsigned char __attribute__((address_space(3))) uc_l;

__device__ __forceinline__ void gl_lds16(const void* g, void* l) {
  __builtin_amdgcn_global_load_lds((const uc_g*)g, (uc_l*)l, 16, 0, 0);
}

// ---------------- f32 -> bf16 convert (vectorized, 8 elems/thread) ----------------
__global__ __launch_bounds__(256) void cvtx_kernel(const float* __restrict__ x,
                                                   bf16_t* __restrict__ xb) {
  const size_t t = (size_t)blockIdx.x * 256 + threadIdx.x;
  const float4 a = ((const float4*)x)[t * 2];
  const float4 b = ((const float4*)x)[t * 2 + 1];
  bf16x8 o;
  o[0] = (bf16_t)a.x; o[1] = (bf16_t)a.y; o[2] = (bf16_t)a.z; o[3] = (bf16_t)a.w;
  o[4] = (bf16_t)b.x; o[5] = (bf16_t)b.y; o[6] = (bf16_t)b.z; o[7] = (bf16_t)b.w;
  *(bf16x8*)(xb + t * 8) = o;
}

// ------- W (E x N, f32) -> rows z*512.. of concatenated WT (1536 x E, bf16) -------
__global__ __launch_bounds__(256) void wtr_kernel(const float* __restrict__ W0,
                                                  const float* __restrict__ W1,
                                                  const float* __restrict__ W2,
                                                  bf16_t* __restrict__ WTall) {
  const int z = blockIdx.z;
  const float* W = z == 0 ? W0 : (z == 1 ? W1 : W2);
  bf16_t* O = WTall + (size_t)z * 512 * E_DIM;
  __shared__ float tile[32][33];
  const int tx = threadIdx.x, ty = threadIdx.y;       // (32,8)
  const int r0 = blockIdx.y * 32, c0 = blockIdx.x * 32;
#pragma unroll
  for (int i = 0; i < 4; ++i)
    tile[ty + i * 8][tx] = W[(size_t)(r0 + ty + i * 8) * E_DIM + c0 + tx];
  __syncthreads();
#pragma unroll
  for (int i = 0; i < 4; ++i)
    O[(size_t)(c0 + ty + i * 8) * E_DIM + r0 + tx] = (bf16_t)tile[tx][ty + i * 8];
}

// ---------------- concat 3 biases into one [1536] f32 -----------------------------
__global__ __launch_bounds__(256) void bcat_kernel(const float* __restrict__ b0,
                                                   const float* __restrict__ b1,
                                                   const float* __restrict__ b2,
                                                   float* __restrict__ bb) {
  const int i = blockIdx.x * 256 + threadIdx.x;   // 0..1535
  bb[i] = i < 512 ? b0[i] : (i < 1024 ? b1[i - 512] : b2[i - 1024]);
}

// ---------------- zero D (B*T floats) ---------------------------------------------
__global__ __launch_bounds__(256) void zero_kernel(float4* __restrict__ p) {
  p[blockIdx.x * 256 + threadIdx.x] = make_float4(0.f, 0.f, 0.f, 0.f);
}

// -------- per-batch bf16 transpose + column normalize: vT[v][s] = v[s][v]/D[s] ----
__global__ __launch_bounds__(512) void vtr_kernel(const bf16_t* __restrict__ Vb,
                                                  const float* __restrict__ Dsum,
                                                  bf16_t* __restrict__ VT, int ldv) {
  const int b = blockIdx.z;
  __shared__ bf16_t tile[64][65];
  const int tx = threadIdx.x, ty = threadIdx.y;       // (64,8)
  const bf16_t* src = Vb + (size_t)b * T_DIM * ldv;
  const float* Ds = Dsum + (size_t)b * T_DIM;
  bf16_t* dst = VT + (size_t)b * T_DIM * T_DIM;
  const int r0 = blockIdx.y * 64, c0 = blockIdx.x * 64;  // r = s index, c = v index
#pragma unroll
  for (int i = 0; i < 8; ++i) {
    const int s = r0 + ty + i * 8;
    const float inv = 1.0f / Ds[s];
    tile[ty + i * 8][tx] = (bf16_t)((float)src[(size_t)s * ldv + c0 + tx] * inv);
  }
  __syncthreads();
#pragma unroll
  for (int i = 0; i < 8; ++i)
    dst[(size_t)(c0 + ty + i * 8) * T_DIM + r0 + tx] = tile[tx][ty + i * 8];
}

// ---------------- NT bf16 MFMA GEMM, 128x128 tile, BK=64, 4 waves -----------------
// C[m][n] = sum_k A[m][k] * Bt[n][k]
// EPI 0: += bias[n], store bf16                       (fused QKV projection)
// EPI 1: e = exp(acc*scale) masked->0, store bf16 P', atomic column-sum into Dsum
//        (skip bn>bm blocks entirely — PV never reads them)
// EPI 2: store f32, causal K-trunc Kend=(bm+1)*128    (PV)
template <int EPI>
__global__ __launch_bounds__(256)
void gemm_nt(const bf16_t* __restrict__ A, const bf16_t* __restrict__ Bt,
             void* __restrict__ Cv, const float* __restrict__ bias,
             float* __restrict__ Dsum,
             int K, int lda, int ldb, int ldc,
             long sA, long sB, long sC, float scale) {
  __shared__ bf16_t lA[128 * 64];
  __shared__ bf16_t lB[128 * 64];
  const int bz = blockIdx.z;
  const int bm = blockIdx.x, bn = blockIdx.y;
  if (EPI == 1 && bn > bm) return;   // fully masked: contributes nothing anywhere

  const int tid = threadIdx.x;
  const int wid = tid >> 6, lane = tid & 63;
  const int wr = wid >> 1, wc = wid & 1;
  const int l15 = lane & 15, lk = lane >> 4;

  const long crow0 = (long)bm * 128 + wr * 64 + lk * 4;
  const int ccol0 = bn * 128 + wc * 64 + l15;

  const bf16_t* Ab = A + (long)bz * sA;
  const bf16_t* Bb = Bt + (long)bz * sB;

  f32x4 acc[4][4] = {};

  const int srow = tid >> 3;        // 0..31 within a 32-row staging chunk
  const int scol = (tid & 7) * 8;   // 0..56
  const bf16_t* gA = Ab + (long)(bm * 128 + srow) * lda + scol;
  const bf16_t* gB = Bb + (long)(bn * 128 + srow) * ldb + scol;
  const int lbase = wid * 512;      // wave-uniform LDS element base

  const int Kend = (EPI == 2) ? (bm + 1) * 128 : K;

  for (int k0 = 0; k0 < Kend; k0 += 64) {
#pragma unroll
    for (int c = 0; c < 4; ++c) {
      gl_lds16(gA + (long)(c * 32) * lda + k0, lA + c * 2048 + lbase);
      gl_lds16(gB + (long)(c * 32) * ldb + k0, lB + c * 2048 + lbase);
    }
    __syncthreads();
#pragma unroll
    for (int ks = 0; ks < 2; ++ks) {
      bf16x8 af[4], bfr[4];
#pragma unroll
      for (int m = 0; m < 4; ++m)
        af[m] = *(const bf16x8*)&lA[(wr * 64 + m * 16 + l15) * 64 + ks * 32 + lk * 8];
#pragma unroll
      for (int n = 0; n < 4; ++n)
        bfr[n] = *(const bf16x8*)&lB[(wc * 64 + n * 16 + l15) * 64 + ks * 32 + lk * 8];
#pragma unroll
      for (int m = 0; m < 4; ++m)
#pragma unroll
        for (int n = 0; n < 4; ++n)
          acc[m][n] = __builtin_amdgcn_mfma_f32_16x16x32_bf16(af[m], bfr[n], acc[m][n], 0, 0, 0);
    }
    __syncthreads();
  }

  if constexpr (EPI == 0) {
    bf16_t* C = (bf16_t*)Cv + (long)bz * sC;
#pragma unroll
    for (int m = 0; m < 4; ++m)
#pragma unroll
      for (int n = 0; n < 4; ++n) {
        const int col = ccol0 + n * 16;
        const float bv = bias[col];
#pragma unroll
        for (int r = 0; r < 4; ++r)
          C[(crow0 + m * 16 + r) * (long)ldc + col] = (bf16_t)(acc[m][n][r] + bv);
      }
  } else if constexpr (EPI == 1) {
    bf16_t* C = (bf16_t*)Cv + (long)bz * sC;
    float ts[4] = {0.f, 0.f, 0.f, 0.f};
#pragma unroll
    for (int m = 0; m < 4; ++m)
#pragma unroll
      for (int n = 0; n < 4; ++n) {
        const int col = ccol0 + n * 16;
#pragma unroll
        for (int r = 0; r < 4; ++r) {
          const long row = crow0 + m * 16 + r;
          float e = 0.f;
          if (col <= row) e = __expf(acc[m][n][r] * scale);  // no max-sub: |score|<~8
          const bf16_t eb = (bf16_t)e;
          C[row * (long)ldc + col] = eb;
          ts[n] += (float)eb;     // sum exactly what PV will consume
        }
      }
    // reduce over lk (lanes l15, l15+16, l15+32, l15+48 hold same column set)
#pragma unroll
    for (int n = 0; n < 4; ++n) {
      ts[n] += __shfl_xor(ts[n], 16);
      ts[n] += __shfl_xor(ts[n], 32);
    }
    float* colsum = (float*)lA;   // K-loop LDS is dead; reuse
    if (tid < 128) colsum[tid] = 0.f;
    __syncthreads();
    if (lk == 0) {                // lanes 0..15 of each of the 4 waves
#pragma unroll
      for (int n = 0; n < 4; ++n)
        atomicAdd(&colsum[wc * 64 + n * 16 + l15], ts[n]);
    }
    __syncthreads();
    if (tid < 128)
      atomicAdd(&Dsum[(long)bz * T_DIM + bn * 128 + tid], colsum[tid]);
  } else {
    float* C = (float*)Cv + (long)bz * sC;
#pragma unroll
    for (int m = 0; m < 4; ++m)
#pragma unroll
      for (int n = 0; n < 4; ++n) {
        const int col = ccol0 + n * 16;
#pragma unroll
        for (int r = 0; r < 4; ++r)
          C[(crow0 + m * 16 + r) * (long)ldc + col] = acc[m][n][r];
      }
  }
}

// ----------------------------------------------------------------------------------
extern "C" void kernel_launch(void* const* d_in, const int* in_sizes, int n_in,
                              void* d_out, int out_size, void* d_ws, size_t ws_size,
                              hipStream_t stream) {
  const float* x  = (const float*)d_in[0];
  const float* Wq = (const float*)d_in[1];
  const float* bq = (const float*)d_in[2];
  const float* Wk = (const float*)d_in[3];
  const float* bk = (const float*)d_in[4];
  const float* Wv = (const float*)d_in[5];
  const float* bv = (const float*)d_in[6];
  float* out = (float*)d_out;

  char* ws = (char*)d_ws;
  const size_t SZ = (size_t)B_DIM * T_DIM * E_DIM * 2;      // 33,554,432 B
  bf16_t* xb    = (bf16_t*)(ws);                            // dead after projection
  bf16_t* P     = (bf16_t*)(ws);                            // overlays xb
  bf16_t* qkv   = (bf16_t*)(ws + SZ);                       // [32768][1536]
  bf16_t* vT    = (bf16_t*)(ws + SZ + 3 * SZ);              // [B][512][512]
  bf16_t* WTall = (bf16_t*)(ws + 5 * SZ);                   // [1536][512]
  float*  bcat  = (float*)(ws + 5 * SZ + 1572864);          // [1536]
  float*  Dsum  = (float*)(ws + 5 * SZ + 1572864 + 8192);   // [B][512]

  const int M = B_DIM * T_DIM;                  // 32768
  const long sQKV = (long)T_DIM * 1536;         // per-batch stride in qkv
  const long bstr = (long)T_DIM * T_DIM;        // per-batch stride, T x T
  const float scale = 1.0f / sqrtf((float)E_DIM);

  // 1. x -> bf16
  cvtx_kernel<<<dim3(8192), dim3(256), 0, stream>>>(x, xb);
  // 2. weight transposes into concatenated [1536][512] + bias concat
  wtr_kernel<<<dim3(16, 16, 3), dim3(32, 8), 0, stream>>>(Wq, Wk, Wv, WTall);
  bcat_kernel<<<dim3(6), dim3(256), 0, stream>>>(bq, bk, bv, bcat);
  // 3. fused QKV projection: [32768][512] x [1536][512]^T -> [32768][1536]
  gemm_nt<0><<<dim3(256, 12, 1), dim3(256), 0, stream>>>(
      xb, WTall, qkv, bcat, nullptr, 512, 512, 512, 1536, 0, 0, 0, 0.f);
  // 4. zero D
  zero_kernel<<<dim3(32), dim3(256), 0, stream>>>((float4*)Dsum);
  // 5. P' = exp(scale * q k^T) masked, bf16; Dsum[b][s] = sum_t P'[t][s]
  gemm_nt<1><<<dim3(4, 4, B_DIM), dim3(256), 0, stream>>>(
      qkv, qkv + 512, P, nullptr, Dsum, 512, 1536, 1536, T_DIM,
      sQKV, sQKV, bstr, scale);
  // 6. vT[b][v][s] = v[b][s][v] / Dsum[b][s]
  vtr_kernel<<<dim3(8, 8, B_DIM), dim3(64, 8), 0, stream>>>(qkv + 1024, Dsum, vT, 1536);
  // 7. out = P' @ vT^T (causal K-truncation), f32
  gemm_nt<2><<<dim3(4, 4, B_DIM), dim3(256), 0, stream>>>(
      P, vT, out, nullptr, nullptr, 512, T_DIM, T_DIM, T_DIM,
      bstr, bstr, bstr, 1.f);
}

// Round 4
// 282.739 us; speedup vs baseline: 1.2827x; 1.0774x over previous
//
#include <hip/hip_runtime.h>
#include <hip/hip_bf16.h>
#include <math.h>

#define B_DIM 64
#define T_DIM 512
#define E_DIM 512   // K = V = 512 too

typedef __bf16 bf16_t;
typedef bf16_t bf16x8 __attribute__((ext_vector_type(8)));
typedef float  f32x4  __attribute__((ext_vector_type(4)));

typedef unsigned char __attribute__((address_space(1))) uc_g;
typedef unsigned char __attribute__((address_space(3))) uc_l;

__device__ __forceinline__ void gl_lds16(const void* g, void* l) {
  __builtin_amdgcn_global_load_lds((const uc_g*)g, (uc_l*)l, 16, 0, 0);
}

// ---------------- f32 -> bf16 convert (vectorized, 8 elems/thread) ----------------
__global__ __launch_bounds__(256) void cvtx_kernel(const float* __restrict__ x,
                                                   bf16_t* __restrict__ xb) {
  const size_t t = (size_t)blockIdx.x * 256 + threadIdx.x;
  const float4 a = ((const float4*)x)[t * 2];
  const float4 b = ((const float4*)x)[t * 2 + 1];
  bf16x8 o;
  o[0] = (bf16_t)a.x; o[1] = (bf16_t)a.y; o[2] = (bf16_t)a.z; o[3] = (bf16_t)a.w;
  o[4] = (bf16_t)b.x; o[5] = (bf16_t)b.y; o[6] = (bf16_t)b.z; o[7] = (bf16_t)b.w;
  *(bf16x8*)(xb + t * 8) = o;
}

// ------- W (E x N, f32) -> rows z*512.. of concatenated WT (1536 x E, bf16) -------
__global__ __launch_bounds__(256) void wtr_kernel(const float* __restrict__ W0,
                                                  const float* __restrict__ W1,
                                                  const float* __restrict__ W2,
                                                  bf16_t* __restrict__ WTall) {
  const int z = blockIdx.z;
  const float* W = z == 0 ? W0 : (z == 1 ? W1 : W2);
  bf16_t* O = WTall + (size_t)z * 512 * E_DIM;
  __shared__ float tile[32][33];
  const int tx = threadIdx.x, ty = threadIdx.y;       // (32,8)
  const int r0 = blockIdx.y * 32, c0 = blockIdx.x * 32;
#pragma unroll
  for (int i = 0; i < 4; ++i)
    tile[ty + i * 8][tx] = W[(size_t)(r0 + ty + i * 8) * E_DIM + c0 + tx];
  __syncthreads();
#pragma unroll
  for (int i = 0; i < 4; ++i)
    O[(size_t)(c0 + ty + i * 8) * E_DIM + r0 + tx] = (bf16_t)tile[tx][ty + i * 8];
}

// ---------------- concat 3 biases into one [1536] f32 -----------------------------
__global__ __launch_bounds__(256) void bcat_kernel(const float* __restrict__ b0,
                                                   const float* __restrict__ b1,
                                                   const float* __restrict__ b2,
                                                   float* __restrict__ bb) {
  const int i = blockIdx.x * 256 + threadIdx.x;   // 0..1535
  bb[i] = i < 512 ? b0[i] : (i < 1024 ? b1[i - 512] : b2[i - 1024]);
}

// ---------------- zero D (B*T floats) ---------------------------------------------
__global__ __launch_bounds__(256) void zero_kernel(float4* __restrict__ p) {
  p[blockIdx.x * 256 + threadIdx.x] = make_float4(0.f, 0.f, 0.f, 0.f);
}

// -------- per-batch bf16 transpose + column normalize: vT[v][s] = v[s][v]/D[s] ----
__global__ __launch_bounds__(512) void vtr_kernel(const bf16_t* __restrict__ Vb,
                                                  const float* __restrict__ Dsum,
                                                  bf16_t* __restrict__ VT, int ldv) {
  const int b = blockIdx.z;
  __shared__ bf16_t tile[64][65];
  const int tx = threadIdx.x, ty = threadIdx.y;       // (64,8)
  const bf16_t* src = Vb + (size_t)b * T_DIM * ldv;
  const float* Ds = Dsum + (size_t)b * T_DIM;
  bf16_t* dst = VT + (size_t)b * T_DIM * T_DIM;
  const int r0 = blockIdx.y * 64, c0 = blockIdx.x * 64;  // r = s index, c = v index
#pragma unroll
  for (int i = 0; i < 8; ++i) {
    const int s = r0 + ty + i * 8;
    const float inv = 1.0f / Ds[s];
    tile[ty + i * 8][tx] = (bf16_t)((float)src[(size_t)s * ldv + c0 + tx] * inv);
  }
  __syncthreads();
#pragma unroll
  for (int i = 0; i < 8; ++i)
    dst[(size_t)(c0 + ty + i * 8) * T_DIM + r0 + tx] = tile[tx][ty + i * 8];
}

// ================== 256x256 pipelined MFMA GEMM for the QKV projection ============
// A: [32768][512] bf16, Bt: [1536][512] bf16, C: [32768][1536] bf16 (+bias).
// 8 waves (2M x 4N), BK=32, 3-deep LDS ring (96 KiB), counted vmcnt(4) pipeline,
// T2 XOR-swizzle (pre-swizzled global src + swizzled ds_read), T5 setprio,
// T1 XCD-aware block swizzle (768 blocks, 768 % 8 == 0).
__global__ __launch_bounds__(512)
void gemm256_qkv(const bf16_t* __restrict__ A, const bf16_t* __restrict__ Bt,
                 bf16_t* __restrict__ C, const float* __restrict__ bias) {
  __shared__ bf16_t lds[3][2][8192];   // [buf][A/B][256 rows x 32 k] = 96 KiB
  const int tid = threadIdx.x;

  int lin = blockIdx.y * 128 + blockIdx.x;        // grid (128, 6)
  lin = (lin & 7) * 96 + (lin >> 3);              // XCD swizzle: same-XCD -> same bn
  const int bm = lin & 127;
  const int bn = lin >> 7;

  // staging lanes: wave w covers 16 rows per round; lane j -> row j>>2, granule j&3
  const int w = tid >> 6, j = tid & 63;
  const int srow = w * 16 + (j >> 2);                       // 0..127 (round 1 adds 128)
  const int scol = ((j & 3) ^ ((j >> 3) & 3)) * 8;          // pre-swizzled source granule
  const bf16_t* gA = A + (long)(bm * 256 + srow) * 512 + scol;
  const bf16_t* gB = Bt + (long)(bn * 256 + srow) * 512 + scol;

  // fragment-read lanes
  const int l15 = tid & 15, lk = (tid >> 4) & 3;
  const int kperm = (lk ^ ((l15 >> 1) & 3)) * 8;            // swizzled read granule
  const int wr = w >> 2, wc = w & 3;                        // 2 x 4 wave grid

#define STG_A(kt, buf) { gl_lds16(gA + (long)(kt) * 32, &lds[buf][0][w * 512]); \
                         gl_lds16(gA + (long)(kt) * 32 + 128 * 512, &lds[buf][0][4096 + w * 512]); }
#define STG_B(kt, buf) { gl_lds16(gB + (long)(kt) * 32, &lds[buf][1][w * 512]); \
                         gl_lds16(gB + (long)(kt) * 32 + 128 * 512, &lds[buf][1][4096 + w * 512]); }

  f32x4 acc[8][4] = {};

  // prologue: tiles 0,1 staged; wait tile 0 landed (vmcnt(4) leaves tile 1 in flight)
  STG_A(0, 0); STG_B(0, 0);
  STG_A(1, 1); STG_B(1, 1);
  asm volatile("s_waitcnt vmcnt(4)" ::: "memory");
  asm volatile("s_barrier" ::: "memory");

  int cb = 0;
  for (int kt = 0; kt < 16; ++kt) {
    const int sb = (cb == 0) ? 2 : cb - 1;        // (kt+2) % 3
    const bf16_t* lA_ = lds[cb][0];
    const bf16_t* lB_ = lds[cb][1];

    // ---- phase 0: B frags + A rows [0,64), stage next A-half --------------------
    bf16x8 bfr[4], af0[4];
#pragma unroll
    for (int n = 0; n < 4; ++n)
      bfr[n] = *(const bf16x8*)&lB_[(wc * 64 + n * 16 + l15) * 32 + kperm];
#pragma unroll
    for (int m = 0; m < 4; ++m)
      af0[m] = *(const bf16x8*)&lA_[(wr * 128 + m * 16 + l15) * 32 + kperm];
    if (kt < 14) STG_A(kt + 2, sb);
    asm volatile("s_barrier" ::: "memory");
    __builtin_amdgcn_s_setprio(1);
#pragma unroll
    for (int m = 0; m < 4; ++m)
#pragma unroll
      for (int n = 0; n < 4; ++n)
        acc[m][n] = __builtin_amdgcn_mfma_f32_16x16x32_bf16(af0[m], bfr[n], acc[m][n], 0, 0, 0);
    __builtin_amdgcn_s_setprio(0);
    asm volatile("s_barrier" ::: "memory");

    // ---- phase 1: A rows [64,128), stage next B-half, K-tile boundary vmcnt ------
    bf16x8 af1[4];
#pragma unroll
    for (int m = 0; m < 4; ++m)
      af1[m] = *(const bf16x8*)&lA_[(wr * 128 + 64 + m * 16 + l15) * 32 + kperm];
    if (kt < 14) STG_B(kt + 2, sb);
    if (kt < 14)       asm volatile("s_waitcnt vmcnt(4)" ::: "memory");  // tile kt+1 landed
    else if (kt == 14) asm volatile("s_waitcnt vmcnt(0)" ::: "memory");  // tile 15 landed
    asm volatile("s_barrier" ::: "memory");
    __builtin_amdgcn_s_setprio(1);
#pragma unroll
    for (int m = 0; m < 4; ++m)
#pragma unroll
      for (int n = 0; n < 4; ++n)
        acc[4 + m][n] = __builtin_amdgcn_mfma_f32_16x16x32_bf16(af1[m], bfr[n], acc[4 + m][n], 0, 0, 0);
    __builtin_amdgcn_s_setprio(0);
    asm volatile("s_barrier" ::: "memory");
    cb = (cb == 2) ? 0 : cb + 1;
  }
#undef STG_A
#undef STG_B

  // epilogue: acc[mm] covers rows wr*128 + mm*16 (mm 4..7 == +64 half)
#pragma unroll
  for (int mm = 0; mm < 8; ++mm) {
    const long row0 = (long)bm * 256 + wr * 128 + mm * 16 + lk * 4;
#pragma unroll
    for (int n = 0; n < 4; ++n) {
      const int col = bn * 256 + wc * 64 + n * 16 + l15;
      const float bv = bias[col];
#pragma unroll
      for (int r = 0; r < 4; ++r)
        C[(row0 + r) * 1536 + col] = (bf16_t)(acc[mm][n][r] + bv);
    }
  }
}

// ---------------- NT bf16 MFMA GEMM, 128x128 tile, BK=64, 4 waves -----------------
// EPI 1: e = exp(acc*scale) masked->0, store bf16 P', atomic column-sum into Dsum
//        (skip bn>bm blocks entirely — PV never reads them)
// EPI 2: store f32, causal K-trunc Kend=(bm+1)*128    (PV)
template <int EPI>
__global__ __launch_bounds__(256)
void gemm_nt(const bf16_t* __restrict__ A, const bf16_t* __restrict__ Bt,
             void* __restrict__ Cv, const float* __restrict__ bias,
             float* __restrict__ Dsum,
             int K, int lda, int ldb, int ldc,
             long sA, long sB, long sC, float scale) {
  __shared__ bf16_t lA[128 * 64];
  __shared__ bf16_t lB[128 * 64];
  const int bz = blockIdx.z;
  const int bm = blockIdx.x, bn = blockIdx.y;
  if (EPI == 1 && bn > bm) return;   // fully masked: contributes nothing anywhere

  const int tid = threadIdx.x;
  const int wid = tid >> 6, lane = tid & 63;
  const int wr = wid >> 1, wc = wid & 1;
  const int l15 = lane & 15, lk = lane >> 4;

  const long crow0 = (long)bm * 128 + wr * 64 + lk * 4;
  const int ccol0 = bn * 128 + wc * 64 + l15;

  const bf16_t* Ab = A + (long)bz * sA;
  const bf16_t* Bb = Bt + (long)bz * sB;

  f32x4 acc[4][4] = {};

  const int srow = tid >> 3;        // 0..31 within a 32-row staging chunk
  const int scol = (tid & 7) * 8;   // 0..56
  const bf16_t* gA = Ab + (long)(bm * 128 + srow) * lda + scol;
  const bf16_t* gB = Bb + (long)(bn * 128 + srow) * ldb + scol;
  const int lbase = wid * 512;      // wave-uniform LDS element base

  const int Kend = (EPI == 2) ? (bm + 1) * 128 : K;

  for (int k0 = 0; k0 < Kend; k0 += 64) {
#pragma unroll
    for (int c = 0; c < 4; ++c) {
      gl_lds16(gA + (long)(c * 32) * lda + k0, lA + c * 2048 + lbase);
      gl_lds16(gB + (long)(c * 32) * ldb + k0, lB + c * 2048 + lbase);
    }
    __syncthreads();
#pragma unroll
    for (int ks = 0; ks < 2; ++ks) {
      bf16x8 af[4], bfr[4];
#pragma unroll
      for (int m = 0; m < 4; ++m)
        af[m] = *(const bf16x8*)&lA[(wr * 64 + m * 16 + l15) * 64 + ks * 32 + lk * 8];
#pragma unroll
      for (int n = 0; n < 4; ++n)
        bfr[n] = *(const bf16x8*)&lB[(wc * 64 + n * 16 + l15) * 64 + ks * 32 + lk * 8];
#pragma unroll
      for (int m = 0; m < 4; ++m)
#pragma unroll
        for (int n = 0; n < 4; ++n)
          acc[m][n] = __builtin_amdgcn_mfma_f32_16x16x32_bf16(af[m], bfr[n], acc[m][n], 0, 0, 0);
    }
    __syncthreads();
  }

  if constexpr (EPI == 1) {
    bf16_t* C = (bf16_t*)Cv + (long)bz * sC;
    float ts[4] = {0.f, 0.f, 0.f, 0.f};
#pragma unroll
    for (int m = 0; m < 4; ++m)
#pragma unroll
      for (int n = 0; n < 4; ++n) {
        const int col = ccol0 + n * 16;
#pragma unroll
        for (int r = 0; r < 4; ++r) {
          const long row = crow0 + m * 16 + r;
          float e = 0.f;
          if (col <= row) e = __expf(acc[m][n][r] * scale);  // no max-sub: |score|<~8
          const bf16_t eb = (bf16_t)e;
          C[row * (long)ldc + col] = eb;
          ts[n] += (float)eb;     // sum exactly what PV will consume
        }
      }
#pragma unroll
    for (int n = 0; n < 4; ++n) {
      ts[n] += __shfl_xor(ts[n], 16);
      ts[n] += __shfl_xor(ts[n], 32);
    }
    float* colsum = (float*)lA;   // K-loop LDS is dead; reuse
    if (tid < 128) colsum[tid] = 0.f;
    __syncthreads();
    if (lk == 0) {                // lanes 0..15 of each of the 4 waves
#pragma unroll
      for (int n = 0; n < 4; ++n)
        atomicAdd(&colsum[wc * 64 + n * 16 + l15], ts[n]);
    }
    __syncthreads();
    if (tid < 128)
      atomicAdd(&Dsum[(long)bz * T_DIM + bn * 128 + tid], colsum[tid]);
  } else {
    float* C = (float*)Cv + (long)bz * sC;
#pragma unroll
    for (int m = 0; m < 4; ++m)
#pragma unroll
      for (int n = 0; n < 4; ++n) {
        const int col = ccol0 + n * 16;
#pragma unroll
        for (int r = 0; r < 4; ++r)
          C[(crow0 + m * 16 + r) * (long)ldc + col] = acc[m][n][r];
      }
  }
}

// ----------------------------------------------------------------------------------
extern "C" void kernel_launch(void* const* d_in, const int* in_sizes, int n_in,
                              void* d_out, int out_size, void* d_ws, size_t ws_size,
                              hipStream_t stream) {
  const float* x  = (const float*)d_in[0];
  const float* Wq = (const float*)d_in[1];
  const float* bq = (const float*)d_in[2];
  const float* Wk = (const float*)d_in[3];
  const float* bk = (const float*)d_in[4];
  const float* Wv = (const float*)d_in[5];
  const float* bv = (const float*)d_in[6];
  float* out = (float*)d_out;

  char* ws = (char*)d_ws;
  const size_t SZ = (size_t)B_DIM * T_DIM * E_DIM * 2;      // 33,554,432 B
  bf16_t* xb    = (bf16_t*)(ws);                            // dead after projection
  bf16_t* P     = (bf16_t*)(ws);                            // overlays xb
  bf16_t* qkv   = (bf16_t*)(ws + SZ);                       // [32768][1536]
  bf16_t* vT    = (bf16_t*)(ws + SZ + 3 * SZ);              // [B][512][512]
  bf16_t* WTall = (bf16_t*)(ws + 5 * SZ);                   // [1536][512]
  float*  bcat  = (float*)(ws + 5 * SZ + 1572864);          // [1536]
  float*  Dsum  = (float*)(ws + 5 * SZ + 1572864 + 8192);   // [B][512]

  const long sQKV = (long)T_DIM * 1536;         // per-batch stride in qkv
  const long bstr = (long)T_DIM * T_DIM;        // per-batch stride, T x T
  const float scale = 1.0f / sqrtf((float)E_DIM);

  // 1. x -> bf16
  cvtx_kernel<<<dim3(8192), dim3(256), 0, stream>>>(x, xb);
  // 2. weight transposes into concatenated [1536][512] + bias concat
  wtr_kernel<<<dim3(16, 16, 3), dim3(32, 8), 0, stream>>>(Wq, Wk, Wv, WTall);
  bcat_kernel<<<dim3(6), dim3(256), 0, stream>>>(bq, bk, bv, bcat);
  // 3. fused QKV projection: pipelined 256x256 kernel
  gemm256_qkv<<<dim3(128, 6), dim3(512), 0, stream>>>(xb, WTall, qkv, bcat);
  // 4. zero D
  zero_kernel<<<dim3(32), dim3(256), 0, stream>>>((float4*)Dsum);
  // 5. P' = exp(scale * q k^T) masked, bf16; Dsum[b][s] = sum_t P'[t][s]
  gemm_nt<1><<<dim3(4, 4, B_DIM), dim3(256), 0, stream>>>(
      qkv, qkv + 512, P, nullptr, Dsum, 512, 1536, 1536, T_DIM,
      sQKV, sQKV, bstr, scale);
  // 6. vT[b][v][s] = v[b][s][v] / Dsum[b][s]
  vtr_kernel<<<dim3(8, 8, B_DIM), dim3(64, 8), 0, stream>>>(qkv + 1024, Dsum, vT, 1536);
  // 7. out = P' @ vT^T (causal K-truncation), f32
  gemm_nt<2><<<dim3(4, 4, B_DIM), dim3(256), 0, stream>>>(
      P, vT, out, nullptr, nullptr, 512, T_DIM, T_DIM, T_DIM,
      bstr, bstr, bstr, 1.f);
}

// Round 5
// 276.036 us; speedup vs baseline: 1.3138x; 1.0243x over previous
//
#include <hip/hip_runtime.h>
#include <hip/hip_bf16.h>
#include <math.h>

#define B_DIM 64
#define T_DIM 512
#define E_DIM 512   // K = V = 512 too

typedef __bf16 bf16_t;
typedef bf16_t bf16x8 __attribute__((ext_vector_type(8)));
typedef float  f32x4  __attribute__((ext_vector_type(4)));

typedef unsigned char __attribute__((address_space(1))) uc_g;
typedef unsigned char __attribute__((address_space(3))) uc_l;

__device__ __forceinline__ void gl_lds16(const void* g, void* l) {
  __builtin_amdgcn_global_load_lds((const uc_g*)g, (uc_l*)l, 16, 0, 0);
}

// ---------------- f32 -> bf16 convert (vectorized, 8 elems/thread) ----------------
__global__ __launch_bounds__(256) void cvtx_kernel(const float* __restrict__ x,
                                                   bf16_t* __restrict__ xb) {
  const size_t t = (size_t)blockIdx.x * 256 + threadIdx.x;
  const float4 a = ((const float4*)x)[t * 2];
  const float4 b = ((const float4*)x)[t * 2 + 1];
  bf16x8 o;
  o[0] = (bf16_t)a.x; o[1] = (bf16_t)a.y; o[2] = (bf16_t)a.z; o[3] = (bf16_t)a.w;
  o[4] = (bf16_t)b.x; o[5] = (bf16_t)b.y; o[6] = (bf16_t)b.z; o[7] = (bf16_t)b.w;
  *(bf16x8*)(xb + t * 8) = o;
}

// ------- W (E x N, f32) -> rows z*512.. of concatenated WT (1536 x E, bf16) -------
__global__ __launch_bounds__(256) void wtr_kernel(const float* __restrict__ W0,
                                                  const float* __restrict__ W1,
                                                  const float* __restrict__ W2,
                                                  bf16_t* __restrict__ WTall) {
  const int z = blockIdx.z;
  const float* W = z == 0 ? W0 : (z == 1 ? W1 : W2);
  bf16_t* O = WTall + (size_t)z * 512 * E_DIM;
  __shared__ float tile[32][33];
  const int tx = threadIdx.x, ty = threadIdx.y;       // (32,8)
  const int r0 = blockIdx.y * 32, c0 = blockIdx.x * 32;
#pragma unroll
  for (int i = 0; i < 4; ++i)
    tile[ty + i * 8][tx] = W[(size_t)(r0 + ty + i * 8) * E_DIM + c0 + tx];
  __syncthreads();
#pragma unroll
  for (int i = 0; i < 4; ++i)
    O[(size_t)(c0 + ty + i * 8) * E_DIM + r0 + tx] = (bf16_t)tile[tx][ty + i * 8];
}

// ---------------- concat 3 biases into one [1536] f32 -----------------------------
__global__ __launch_bounds__(256) void bcat_kernel(const float* __restrict__ b0,
                                                   const float* __restrict__ b1,
                                                   const float* __restrict__ b2,
                                                   float* __restrict__ bb) {
  const int i = blockIdx.x * 256 + threadIdx.x;   // 0..1535
  bb[i] = i < 512 ? b0[i] : (i < 1024 ? b1[i - 512] : b2[i - 1024]);
}

// ---------------- zero D (B*T floats) ---------------------------------------------
__global__ __launch_bounds__(256) void zero_kernel(float4* __restrict__ p) {
  p[blockIdx.x * 256 + threadIdx.x] = make_float4(0.f, 0.f, 0.f, 0.f);
}

// -------- per-batch bf16 transpose + column normalize: vT[v][s] = v[s][v]/D[s] ----
__global__ __launch_bounds__(512) void vtr_kernel(const bf16_t* __restrict__ Vb,
                                                  const float* __restrict__ Dsum,
                                                  bf16_t* __restrict__ VT, int ldv) {
  const int b = blockIdx.z;
  __shared__ bf16_t tile[64][65];
  const int tx = threadIdx.x, ty = threadIdx.y;       // (64,8)
  const bf16_t* src = Vb + (size_t)b * T_DIM * ldv;
  const float* Ds = Dsum + (size_t)b * T_DIM;
  bf16_t* dst = VT + (size_t)b * T_DIM * T_DIM;
  const int r0 = blockIdx.y * 64, c0 = blockIdx.x * 64;  // r = s index, c = v index
#pragma unroll
  for (int i = 0; i < 8; ++i) {
    const int s = r0 + ty + i * 8;
    const float inv = 1.0f / Ds[s];
    tile[ty + i * 8][tx] = (bf16_t)((float)src[(size_t)s * ldv + c0 + tx] * inv);
  }
  __syncthreads();
#pragma unroll
  for (int i = 0; i < 8; ++i)
    dst[(size_t)(c0 + ty + i * 8) * T_DIM + r0 + tx] = tile[tx][ty + i * 8];
}

// ============ unified pipelined NT MFMA GEMM: 128x256 tile, BK=32, ring-3 =========
// 8 waves (2M x 4N, per-wave 64x64), 72 KiB LDS (2 blocks/CU), counted vmcnt(3),
// both-sides XOR swizzle pg = g ^ ((row>>1)&3), T5 setprio.
// EPI 0: projection. grid 1536 1-D; bn-fastest chunked XCD swizzle (L2 A-reuse x6).
//        C = bf16 qkv [32768][1536], += bias.
// EPI 1: scores. grid (4,2,64). skip 2*bn>bm. P'=exp(acc*scale) masked->0 (bf16),
//        column sums atomically into Dsum.
// EPI 2: PV. grid (4,2,64). K-trunc NT=(bm+1)*4. C = f32 out [512][512] per batch.
template <int EPI>
__global__ __launch_bounds__(512)
void gemm_p(const bf16_t* __restrict__ A, const bf16_t* __restrict__ Bt,
            void* __restrict__ Cv, const float* __restrict__ bias,
            float* __restrict__ Dsum,
            int lda, int ldb, int ldc, long sA, long sB, long sC, float scale) {
  __shared__ bf16_t lds[3][12288];   // [buf][A 128x32 | B 256x32] = 72 KiB
  const int tid = threadIdx.x;

  int bm, bn, bz, NT;
  if (EPI == 0) {
    const int lin = blockIdx.x;                    // 1536 blocks
    const int nl = (lin & 7) * 192 + (lin >> 3);   // chunked XCD swizzle
    bm = nl / 6; bn = nl - bm * 6;                 // bn-fastest: A-tile reused x6 in-XCD
    bz = 0; NT = 16;
  } else {
    bm = blockIdx.x; bn = blockIdx.y; bz = blockIdx.z;
    if (EPI == 1 && 2 * bn > bm) return;           // fully masked score block
    NT = (EPI == 2) ? (bm + 1) * 4 : 16;           // causal K-truncation for PV
  }

  const bf16_t* Ab = A + bz * sA + (long)bm * 128 * lda;
  const bf16_t* Bb = Bt + bz * sB + (long)bn * 256 * ldb;

  // staging: thread -> (row = tid>>2, granule g = tid&3); source granule pre-swizzled
  const int strow = tid >> 2, stg = tid & 3;
  const int sgg = stg ^ ((strow >> 1) & 3);
  const bf16_t* gA  = Ab + (long)strow * lda + sgg * 8;
  const bf16_t* gB0 = Bb + (long)strow * ldb + sgg * 8;
  const bf16_t* gB1 = gB0 + (long)128 * ldb;

#define STAGE(kt, buf) { gl_lds16(gA  + (long)(kt) * 32, &lds[buf][tid * 8]);        \
                         gl_lds16(gB0 + (long)(kt) * 32, &lds[buf][4096 + tid * 8]); \
                         gl_lds16(gB1 + (long)(kt) * 32, &lds[buf][8192 + tid * 8]); }

  // fragment-read offsets (swizzled): elem = row*32 + (lk ^ ((row>>1)&3))*8
  const int l15 = tid & 15, lk = (tid >> 4) & 3;
  const int w = tid >> 6, wr = w >> 2, wc = w & 3;
  int aoff[4], boff[4];
#pragma unroll
  for (int m = 0; m < 4; ++m) {
    const int row = wr * 64 + m * 16 + l15;
    aoff[m] = row * 32 + (lk ^ ((row >> 1) & 3)) * 8;
  }
#pragma unroll
  for (int n = 0; n < 4; ++n) {
    const int row = wc * 64 + n * 16 + l15;
    boff[n] = 4096 + row * 32 + (lk ^ ((row >> 1) & 3)) * 8;
  }

  f32x4 acc[4][4] = {};

  STAGE(0, 0); STAGE(1, 1);
  asm volatile("s_waitcnt vmcnt(3)" ::: "memory");   // tile 0 landed; tile 1 in flight
  asm volatile("s_barrier" ::: "memory");

  int cb = 0;
  for (int kt = 0; kt < NT; ++kt) {
    bf16x8 af[4], bfr[4];
#pragma unroll
    for (int m = 0; m < 4; ++m) af[m] = *(const bf16x8*)&lds[cb][aoff[m]];
#pragma unroll
    for (int n = 0; n < 4; ++n) bfr[n] = *(const bf16x8*)&lds[cb][boff[n]];
    const int sb = (cb == 0) ? 2 : cb - 1;           // (kt+2) % 3
    if (kt + 2 < NT) {
      STAGE(kt + 2, sb);
      asm volatile("s_waitcnt vmcnt(3)" ::: "memory");  // tile kt+1 landed
    } else if (kt + 2 == NT) {
      asm volatile("s_waitcnt vmcnt(0)" ::: "memory");  // last tile landed
    }
    asm volatile("s_barrier" ::: "memory");
    __builtin_amdgcn_s_setprio(1);
#pragma unroll
    for (int m = 0; m < 4; ++m)
#pragma unroll
      for (int n = 0; n < 4; ++n)
        acc[m][n] = __builtin_amdgcn_mfma_f32_16x16x32_bf16(af[m], bfr[n], acc[m][n], 0, 0, 0);
    __builtin_amdgcn_s_setprio(0);
    asm volatile("s_barrier" ::: "memory");
    cb = (cb == 2) ? 0 : cb + 1;
  }
#undef STAGE

  // ---- epilogues; C/D layout: col = lane&15, row = lk*4 + r ----------------------
  if constexpr (EPI == 0) {
    bf16_t* C = (bf16_t*)Cv;
#pragma unroll
    for (int m = 0; m < 4; ++m) {
      const long row0 = (long)bm * 128 + wr * 64 + m * 16 + lk * 4;
#pragma unroll
      for (int n = 0; n < 4; ++n) {
        const int col = bn * 256 + wc * 64 + n * 16 + l15;
        const float bv = bias[col];
#pragma unroll
        for (int r = 0; r < 4; ++r)
          C[(row0 + r) * (long)ldc + col] = (bf16_t)(acc[m][n][r] + bv);
      }
    }
  } else if constexpr (EPI == 1) {
    bf16_t* C = (bf16_t*)Cv + bz * sC;
    float ts[4] = {0.f, 0.f, 0.f, 0.f};
#pragma unroll
    for (int m = 0; m < 4; ++m) {
      const long row0 = (long)bm * 128 + wr * 64 + m * 16 + lk * 4;
#pragma unroll
      for (int n = 0; n < 4; ++n) {
        const int lcol = wc * 64 + n * 16 + l15;
        const int col = bn * 256 + lcol;
#pragma unroll
        for (int r = 0; r < 4; ++r) {
          const long row = row0 + r;
          float e = 0.f;
          if (col <= row) e = __expf(acc[m][n][r] * scale);  // no max-sub: |score|<~8
          const bf16_t eb = (bf16_t)e;
          C[row * (long)ldc + col] = eb;
          ts[n] += (float)eb;     // sum exactly what PV will consume
        }
      }
    }
#pragma unroll
    for (int n = 0; n < 4; ++n) {      // reduce over lk groups (same column set)
      ts[n] += __shfl_xor(ts[n], 16);
      ts[n] += __shfl_xor(ts[n], 32);
    }
    float* colsum = (float*)&lds[0][0];   // K-loop LDS dead; reuse
    if (tid < 256) colsum[tid] = 0.f;
    __syncthreads();
    if (lk == 0) {                        // one lane per (wave, l15)
#pragma unroll
      for (int n = 0; n < 4; ++n)
        atomicAdd(&colsum[wc * 64 + n * 16 + l15], ts[n]);
    }
    __syncthreads();
    if (tid < 256)
      atomicAdd(&Dsum[(long)bz * T_DIM + bn * 256 + tid], colsum[tid]);
  } else {
    float* C = (float*)Cv + bz * sC;
#pragma unroll
    for (int m = 0; m < 4; ++m) {
      const long row0 = (long)bm * 128 + wr * 64 + m * 16 + lk * 4;
#pragma unroll
      for (int n = 0; n < 4; ++n) {
        const int col = bn * 256 + wc * 64 + n * 16 + l15;
#pragma unroll
        for (int r = 0; r < 4; ++r)
          C[(row0 + r) * (long)ldc + col] = acc[m][n][r];
      }
    }
  }
}

// ----------------------------------------------------------------------------------
extern "C" void kernel_launch(void* const* d_in, const int* in_sizes, int n_in,
                              void* d_out, int out_size, void* d_ws, size_t ws_size,
                              hipStream_t stream) {
  const float* x  = (const float*)d_in[0];
  const float* Wq = (const float*)d_in[1];
  const float* bq = (const float*)d_in[2];
  const float* Wk = (const float*)d_in[3];
  const float* bk = (const float*)d_in[4];
  const float* Wv = (const float*)d_in[5];
  const float* bv = (const float*)d_in[6];
  float* out = (float*)d_out;

  char* ws = (char*)d_ws;
  const size_t SZ = (size_t)B_DIM * T_DIM * E_DIM * 2;      // 33,554,432 B
  bf16_t* xb    = (bf16_t*)(ws);                            // dead after projection
  bf16_t* P     = (bf16_t*)(ws);                            // overlays xb
  bf16_t* qkv   = (bf16_t*)(ws + SZ);                       // [32768][1536]
  bf16_t* vT    = (bf16_t*)(ws + SZ + 3 * SZ);              // [B][512][512]
  bf16_t* WTall = (bf16_t*)(ws + 5 * SZ);                   // [1536][512]
  float*  bcat  = (float*)(ws + 5 * SZ + 1572864);          // [1536]
  float*  Dsum  = (float*)(ws + 5 * SZ + 1572864 + 8192);   // [B][512]

  const long sQKV = (long)T_DIM * 1536;         // per-batch stride in qkv
  const long bstr = (long)T_DIM * T_DIM;        // per-batch stride, T x T
  const float scale = 1.0f / sqrtf((float)E_DIM);

  // 1. x -> bf16
  cvtx_kernel<<<dim3(8192), dim3(256), 0, stream>>>(x, xb);
  // 2. weight transposes into concatenated [1536][512] + bias concat
  wtr_kernel<<<dim3(16, 16, 3), dim3(32, 8), 0, stream>>>(Wq, Wk, Wv, WTall);
  bcat_kernel<<<dim3(6), dim3(256), 0, stream>>>(bq, bk, bv, bcat);
  // 3. fused QKV projection: [32768][512] x [1536][512]^T -> [32768][1536] (+bias)
  gemm_p<0><<<dim3(1536), dim3(512), 0, stream>>>(
      xb, WTall, qkv, bcat, nullptr, 512, 512, 1536, 0, 0, 0, 0.f);
  // 4. zero D
  zero_kernel<<<dim3(32), dim3(256), 0, stream>>>((float4*)Dsum);
  // 5. P' = exp(scale * q k^T) masked, bf16; Dsum[b][s] = sum_t P'[t][s]
  gemm_p<1><<<dim3(4, 2, B_DIM), dim3(512), 0, stream>>>(
      qkv, qkv + 512, P, nullptr, Dsum, 1536, 1536, T_DIM, sQKV, sQKV, bstr, scale);
  // 6. vT[b][v][s] = v[b][s][v] / Dsum[b][s]
  vtr_kernel<<<dim3(8, 8, B_DIM), dim3(64, 8), 0, stream>>>(qkv + 1024, Dsum, vT, 1536);
  // 7. out = P' @ vT^T (causal K-truncation), f32
  gemm_p<2><<<dim3(4, 2, B_DIM), dim3(512), 0, stream>>>(
      P, vT, out, nullptr, nullptr, 512, 512, T_DIM, bstr, bstr, bstr, 1.f);
}

// Round 6
// 273.542 us; speedup vs baseline: 1.3258x; 1.0091x over previous
//
#include <hip/hip_runtime.h>
#include <hip/hip_bf16.h>
#include <math.h>

#define B_DIM 64
#define T_DIM 512
#define E_DIM 512   // K = V = 512 too

typedef __bf16 bf16_t;
typedef bf16_t bf16x8 __attribute__((ext_vector_type(8)));
typedef float  f32x4  __attribute__((ext_vector_type(4)));

typedef unsigned char __attribute__((address_space(1))) uc_g;
typedef unsigned char __attribute__((address_space(3))) uc_l;

__device__ __forceinline__ void gl_lds16(const void* g, void* l) {
  __builtin_amdgcn_global_load_lds((const uc_g*)g, (uc_l*)l, 16, 0, 0);
}

// ============== fused prep: x->bf16 | 3x W transpose->bf16 | bias concat | zero D ==
// grid: [0,8192) cvtx | [8192,8960) wtr | 8960 bcat | [8961,8993) zero Dsum
__global__ __launch_bounds__(256)
void prep_kernel(const float* __restrict__ x,
                 const float* __restrict__ Wq, const float* __restrict__ Wk,
                 const float* __restrict__ Wv,
                 const float* __restrict__ bq, const float* __restrict__ bk,
                 const float* __restrict__ bv,
                 bf16_t* __restrict__ xb, bf16_t* __restrict__ WTall,
                 float* __restrict__ bcat, float* __restrict__ Dsum) {
  __shared__ float tile[32][33];
  const int bx = blockIdx.x;
  const int t = threadIdx.x;
  if (bx < 8192) {                    // ---- x -> bf16, 8 elems/thread
    const size_t i = (size_t)bx * 256 + t;
    const float4 a = ((const float4*)x)[i * 2];
    const float4 b = ((const float4*)x)[i * 2 + 1];
    bf16x8 o;
    o[0] = (bf16_t)a.x; o[1] = (bf16_t)a.y; o[2] = (bf16_t)a.z; o[3] = (bf16_t)a.w;
    o[4] = (bf16_t)b.x; o[5] = (bf16_t)b.y; o[6] = (bf16_t)b.z; o[7] = (bf16_t)b.w;
    *(bf16x8*)(xb + i * 8) = o;
  } else if (bx < 8960) {             // ---- W (E x N) -> WT rows (N x E), bf16
    const int bid = bx - 8192;        // 0..767
    const int z = bid >> 8;           // which weight
    const int tl = bid & 255;
    const int c0 = (tl & 15) * 32, r0 = (tl >> 4) * 32;
    const float* W = z == 0 ? Wq : (z == 1 ? Wk : Wv);
    bf16_t* O = WTall + (size_t)z * 512 * E_DIM;
    const int tx = t & 31, ty = t >> 5;
#pragma unroll
    for (int i = 0; i < 4; ++i)
      tile[ty + i * 8][tx] = W[(size_t)(r0 + ty + i * 8) * E_DIM + c0 + tx];
    __syncthreads();
#pragma unroll
    for (int i = 0; i < 4; ++i)
      O[(size_t)(c0 + ty + i * 8) * E_DIM + r0 + tx] = (bf16_t)tile[tx][ty + i * 8];
  } else if (bx == 8960) {            // ---- bias concat [1536]
#pragma unroll
    for (int i = t; i < 1536; i += 256)
      bcat[i] = i < 512 ? bq[i] : (i < 1024 ? bk[i - 512] : bv[i - 1024]);
  } else {                            // ---- zero Dsum (32768 floats = 8192 float4)
    const int i = (bx - 8961) * 256 + t;
    ((float4*)Dsum)[i] = make_float4(0.f, 0.f, 0.f, 0.f);
  }
}

// -------- per-batch bf16 transpose + column normalize: vT[v][s] = v[s][v]/D[s] ----
__global__ __launch_bounds__(512) void vtr_kernel(const bf16_t* __restrict__ Vb,
                                                  const float* __restrict__ Dsum,
                                                  bf16_t* __restrict__ VT, int ldv) {
  const int b = blockIdx.z;
  __shared__ bf16_t tile[64][65];
  const int tx = threadIdx.x, ty = threadIdx.y;       // (64,8)
  const bf16_t* src = Vb + (size_t)b * T_DIM * ldv;
  const float* Ds = Dsum + (size_t)b * T_DIM;
  bf16_t* dst = VT + (size_t)b * T_DIM * T_DIM;
  const int r0 = blockIdx.y * 64, c0 = blockIdx.x * 64;  // r = s index, c = v index
#pragma unroll
  for (int i = 0; i < 8; ++i) {
    const int s = r0 + ty + i * 8;
    const float inv = 1.0f / Ds[s];
    tile[ty + i * 8][tx] = (bf16_t)((float)src[(size_t)s * ldv + c0 + tx] * inv);
  }
  __syncthreads();
#pragma unroll
  for (int i = 0; i < 8; ++i)
    dst[(size_t)(c0 + ty + i * 8) * T_DIM + r0 + tx] = tile[tx][ty + i * 8];
}

// ============== 8-phase 256x256 BK=64 pipelined projection GEMM ====================
// A [32768][512], Bt [1536][512] -> C [32768][1536] bf16 (+bias).
// 8 waves (2M x 4N, per-wave 128x64), 2x64KB dbuf (128 KiB), K-tile split in
// k-halves of 32; per phase: {ds_read frags | stage 1 half-tile | barrier |
// setprio MFMA x16 | barrier}; counted vmcnt(6) only at K-tile boundaries.
// Staging order (strictly barrier-separated from last readers):
//   q0: Ak1(kt+1)  q1: Bk0(kt+2)  q2: Ak0(kt+2)  q3: Bk1(kt+2)
// LDS element regions per buffer (32768 elems): Ak0 +0, Ak1 +8192, Bk0 +16384,
// Bk1 +24576. Swizzle (verified r4/r5): granule' = g ^ ((row>>1)&3), 64B rows.
__global__ __launch_bounds__(512)
void gemm8p_qkv(const bf16_t* __restrict__ A, const bf16_t* __restrict__ Bt,
                bf16_t* __restrict__ C, const float* __restrict__ bias) {
  __shared__ bf16_t lds[65536];   // 128 KiB
  const int tid = threadIdx.x;

  const int lin = blockIdx.x;                      // 768 blocks
  const int nl = (lin & 7) * 96 + (lin >> 3);      // bijective XCD chunking
  const int bm = nl / 6, bn = nl - bm * 6;         // bn-fastest: A-tile L2-reuse x6

  // staging lanes: load l covers rows l*128 + tid>>2, 16B granule tid&3 (swizzled src)
  const int sg = (tid & 3) ^ ((tid >> 3) & 3);
  const bf16_t* gA = A + ((long)bm * 256 + (tid >> 2)) * 512 + sg * 8;
  const bf16_t* gB = Bt + ((long)bn * 256 + (tid >> 2)) * 512 + sg * 8;

#define STG(T, regoff, gp, kh) {                                          \
    bf16_t* d_ = &lds[(((T) & 1) << 15) + (regoff) + tid * 8];            \
    gl_lds16((gp) + (long)(T) * 64 + (kh) * 32, d_);                      \
    gl_lds16((gp) + (long)(T) * 64 + (kh) * 32 + (long)128 * 512, d_ + 4096); }
#define STG_Ak0(T) STG(T, 0,     gA, 0)
#define STG_Ak1(T) STG(T, 8192,  gA, 1)
#define STG_Bk0(T) STG(T, 16384, gB, 0)
#define STG_Bk1(T) STG(T, 24576, gB, 1)

  // fragment-read offsets (relative to region base), swizzled
  const int l15 = tid & 15, lk = (tid >> 4) & 3;
  const int w = tid >> 6, wr = w >> 2, wc = w & 3;
  int aoffs[8], boffs[4];
#pragma unroll
  for (int mm = 0; mm < 8; ++mm) {
    const int row = wr * 128 + mm * 16 + l15;
    aoffs[mm] = row * 32 + (lk ^ ((row >> 1) & 3)) * 8;
  }
#pragma unroll
  for (int n = 0; n < 4; ++n) {
    const int row = wc * 64 + n * 16 + l15;
    boffs[n] = row * 32 + (lk ^ ((row >> 1) & 3)) * 8;
  }

  f32x4 acc[8][4] = {};

  // prologue: tile0 complete + tile1 {Bk0,Ak0,Bk1} = 14 loads; vmcnt(6) -> tile0 in
  STG_Bk0(0); STG_Ak0(0); STG_Bk1(0); STG_Ak1(0);
  STG_Bk0(1); STG_Ak0(1); STG_Bk1(1);
  asm volatile("s_waitcnt vmcnt(6)" ::: "memory");
  asm volatile("s_barrier" ::: "memory");

#define MFMA16(BASE, AF, BF)                                                    \
  __builtin_amdgcn_s_setprio(1);                                                \
  _Pragma("unroll") for (int m_ = 0; m_ < 4; ++m_)                              \
    _Pragma("unroll") for (int n_ = 0; n_ < 4; ++n_)                            \
      acc[(BASE) + m_][n_] =                                                    \
        __builtin_amdgcn_mfma_f32_16x16x32_bf16(AF[m_], BF[n_], acc[(BASE) + m_][n_], 0, 0, 0); \
  __builtin_amdgcn_s_setprio(0);

  for (int kt = 0; kt < 8; ++kt) {
    const int bb = (kt & 1) << 15;
    bf16x8 a[4], b0[4], b1[4];

    // ---- phase 0: ks=0, rows 0-63 of wave's half ---------------------------------
#pragma unroll
    for (int n = 0; n < 4; ++n) b0[n] = *(const bf16x8*)&lds[bb + 16384 + boffs[n]];
#pragma unroll
    for (int m = 0; m < 4; ++m) a[m] = *(const bf16x8*)&lds[bb + aoffs[m]];
    if (kt + 1 < 8) STG_Ak1(kt + 1);
    asm volatile("s_barrier" ::: "memory");
    MFMA16(0, a, b0);
    asm volatile("s_barrier" ::: "memory");

    // ---- phase 1: ks=0, rows 64-127 ----------------------------------------------
#pragma unroll
    for (int m = 0; m < 4; ++m) a[m] = *(const bf16x8*)&lds[bb + aoffs[4 + m]];
    if (kt + 2 < 8) STG_Bk0(kt + 2);
    asm volatile("s_barrier" ::: "memory");
    MFMA16(4, a, b0);
    asm volatile("s_barrier" ::: "memory");

    // ---- phase 2: ks=1, rows 0-63 ------------------------------------------------
#pragma unroll
    for (int n = 0; n < 4; ++n) b1[n] = *(const bf16x8*)&lds[bb + 24576 + boffs[n]];
#pragma unroll
    for (int m = 0; m < 4; ++m) a[m] = *(const bf16x8*)&lds[bb + 8192 + aoffs[m]];
    if (kt + 2 < 8) STG_Ak0(kt + 2);
    asm volatile("s_barrier" ::: "memory");
    MFMA16(0, a, b1);
    asm volatile("s_barrier" ::: "memory");

    // ---- phase 3: ks=1, rows 64-127; K-tile boundary wait ------------------------
#pragma unroll
    for (int m = 0; m < 4; ++m) a[m] = *(const bf16x8*)&lds[bb + 8192 + aoffs[4 + m]];
    if (kt + 2 < 8) {
      STG_Bk1(kt + 2);
      asm volatile("s_waitcnt vmcnt(6)" ::: "memory");   // tile kt+1 fully resident
    } else if (kt + 1 < 8) {
      asm volatile("s_waitcnt vmcnt(0)" ::: "memory");   // drain before last tile
    }
    asm volatile("s_barrier" ::: "memory");
    MFMA16(4, a, b1);
    asm volatile("s_barrier" ::: "memory");
  }
#undef MFMA16
#undef STG_Ak0
#undef STG_Ak1
#undef STG_Bk0
#undef STG_Bk1
#undef STG

  // epilogue: rows bm*256 + wr*128 + mm*16 + lk*4 + r; cols bn*256 + wc*64 + n*16 + l15
#pragma unroll
  for (int mm = 0; mm < 8; ++mm) {
    const long row0 = (long)bm * 256 + wr * 128 + mm * 16 + lk * 4;
#pragma unroll
    for (int n = 0; n < 4; ++n) {
      const int col = bn * 256 + wc * 64 + n * 16 + l15;
      const float bv = bias[col];
#pragma unroll
      for (int r = 0; r < 4; ++r)
        C[(row0 + r) * 1536 + col] = (bf16_t)(acc[mm][n][r] + bv);
    }
  }
}

// ============ unified pipelined NT MFMA GEMM: 128x256 tile, BK=32, ring-3 =========
// (round-5 verified; used for scores EPI=1 and PV EPI=2)
template <int EPI>
__global__ __launch_bounds__(512)
void gemm_p(const bf16_t* __restrict__ A, const bf16_t* __restrict__ Bt,
            void* __restrict__ Cv, const float* __restrict__ bias,
            float* __restrict__ Dsum,
            int lda, int ldb, int ldc, long sA, long sB, long sC, float scale) {
  __shared__ bf16_t lds[3][12288];   // [buf][A 128x32 | B 256x32] = 72 KiB
  const int tid = threadIdx.x;

  int bm, bn, bz, NT;
  bm = blockIdx.x; bn = blockIdx.y; bz = blockIdx.z;
  if (EPI == 1 && 2 * bn > bm) return;           // fully masked score block
  NT = (EPI == 2) ? (bm + 1) * 4 : 16;           // causal K-truncation for PV

  const bf16_t* Ab = A + bz * sA + (long)bm * 128 * lda;
  const bf16_t* Bb = Bt + bz * sB + (long)bn * 256 * ldb;

  const int strow = tid >> 2, stg = tid & 3;
  const int sgg = stg ^ ((strow >> 1) & 3);
  const bf16_t* gA  = Ab + (long)strow * lda + sgg * 8;
  const bf16_t* gB0 = Bb + (long)strow * ldb + sgg * 8;
  const bf16_t* gB1 = gB0 + (long)128 * ldb;

#define STAGE(kt, buf) { gl_lds16(gA  + (long)(kt) * 32, &lds[buf][tid * 8]);        \
                         gl_lds16(gB0 + (long)(kt) * 32, &lds[buf][4096 + tid * 8]); \
                         gl_lds16(gB1 + (long)(kt) * 32, &lds[buf][8192 + tid * 8]); }

  const int l15 = tid & 15, lk = (tid >> 4) & 3;
  const int w = tid >> 6, wr = w >> 2, wc = w & 3;
  int aoff[4], boff[4];
#pragma unroll
  for (int m = 0; m < 4; ++m) {
    const int row = wr * 64 + m * 16 + l15;
    aoff[m] = row * 32 + (lk ^ ((row >> 1) & 3)) * 8;
  }
#pragma unroll
  for (int n = 0; n < 4; ++n) {
    const int row = wc * 64 + n * 16 + l15;
    boff[n] = 4096 + row * 32 + (lk ^ ((row >> 1) & 3)) * 8;
  }

  f32x4 acc[4][4] = {};

  STAGE(0, 0); STAGE(1, 1);
  asm volatile("s_waitcnt vmcnt(3)" ::: "memory");
  asm volatile("s_barrier" ::: "memory");

  int cb = 0;
  for (int kt = 0; kt < NT; ++kt) {
    bf16x8 af[4], bfr[4];
#pragma unroll
    for (int m = 0; m < 4; ++m) af[m] = *(const bf16x8*)&lds[cb][aoff[m]];
#pragma unroll
    for (int n = 0; n < 4; ++n) bfr[n] = *(const bf16x8*)&lds[cb][boff[n]];
    const int sb = (cb == 0) ? 2 : cb - 1;
    if (kt + 2 < NT) {
      STAGE(kt + 2, sb);
      asm volatile("s_waitcnt vmcnt(3)" ::: "memory");
    } else if (kt + 2 == NT) {
      asm volatile("s_waitcnt vmcnt(0)" ::: "memory");
    }
    asm volatile("s_barrier" ::: "memory");
    __builtin_amdgcn_s_setprio(1);
#pragma unroll
    for (int m = 0; m < 4; ++m)
#pragma unroll
      for (int n = 0; n < 4; ++n)
        acc[m][n] = __builtin_amdgcn_mfma_f32_16x16x32_bf16(af[m], bfr[n], acc[m][n], 0, 0, 0);
    __builtin_amdgcn_s_setprio(0);
    asm volatile("s_barrier" ::: "memory");
    cb = (cb == 2) ? 0 : cb + 1;
  }
#undef STAGE

  if constexpr (EPI == 1) {
    bf16_t* C = (bf16_t*)Cv + bz * sC;
    float ts[4] = {0.f, 0.f, 0.f, 0.f};
#pragma unroll
    for (int m = 0; m < 4; ++m) {
      const long row0 = (long)bm * 128 + wr * 64 + m * 16 + lk * 4;
#pragma unroll
      for (int n = 0; n < 4; ++n) {
        const int col = bn * 256 + wc * 64 + n * 16 + l15;
#pragma unroll
        for (int r = 0; r < 4; ++r) {
          const long row = row0 + r;
          float e = 0.f;
          if (col <= row) e = __expf(acc[m][n][r] * scale);  // no max-sub: |score|<~8
          const bf16_t eb = (bf16_t)e;
          C[row * (long)ldc + col] = eb;
          ts[n] += (float)eb;
        }
      }
    }
#pragma unroll
    for (int n = 0; n < 4; ++n) {
      ts[n] += __shfl_xor(ts[n], 16);
      ts[n] += __shfl_xor(ts[n], 32);
    }
    float* colsum = (float*)&lds[0][0];
    if (tid < 256) colsum[tid] = 0.f;
    __syncthreads();
    if (lk == 0) {
#pragma unroll
      for (int n = 0; n < 4; ++n)
        atomicAdd(&colsum[wc * 64 + n * 16 + l15], ts[n]);
    }
    __syncthreads();
    if (tid < 256)
      atomicAdd(&Dsum[(long)bz * T_DIM + bn * 256 + tid], colsum[tid]);
  } else {
    float* C = (float*)Cv + bz * sC;
#pragma unroll
    for (int m = 0; m < 4; ++m) {
      const long row0 = (long)bm * 128 + wr * 64 + m * 16 + lk * 4;
#pragma unroll
      for (int n = 0; n < 4; ++n) {
        const int col = bn * 256 + wc * 64 + n * 16 + l15;
#pragma unroll
        for (int r = 0; r < 4; ++r)
          C[(row0 + r) * (long)ldc + col] = acc[m][n][r];
      }
    }
  }
}

// ----------------------------------------------------------------------------------
extern "C" void kernel_launch(void* const* d_in, const int* in_sizes, int n_in,
                              void* d_out, int out_size, void* d_ws, size_t ws_size,
                              hipStream_t stream) {
  const float* x  = (const float*)d_in[0];
  const float* Wq = (const float*)d_in[1];
  const float* bq = (const float*)d_in[2];
  const float* Wk = (const float*)d_in[3];
  const float* bk = (const float*)d_in[4];
  const float* Wv = (const float*)d_in[5];
  const float* bv = (const float*)d_in[6];
  float* out = (float*)d_out;

  char* ws = (char*)d_ws;
  const size_t SZ = (size_t)B_DIM * T_DIM * E_DIM * 2;      // 33,554,432 B
  bf16_t* xb    = (bf16_t*)(ws);                            // dead after projection
  bf16_t* P     = (bf16_t*)(ws);                            // overlays xb
  bf16_t* qkv   = (bf16_t*)(ws + SZ);                       // [32768][1536]
  bf16_t* vT    = (bf16_t*)(ws + SZ + 3 * SZ);              // [B][512][512]
  bf16_t* WTall = (bf16_t*)(ws + 5 * SZ);                   // [1536][512]
  float*  bcat  = (float*)(ws + 5 * SZ + 1572864);          // [1536]
  float*  Dsum  = (float*)(ws + 5 * SZ + 1572864 + 8192);   // [B][512]

  const long sQKV = (long)T_DIM * 1536;         // per-batch stride in qkv
  const long bstr = (long)T_DIM * T_DIM;        // per-batch stride, T x T
  const float scale = 1.0f / sqrtf((float)E_DIM);

  // 1. fused prep: x->bf16, W transposes, bias concat, zero Dsum
  prep_kernel<<<dim3(8993), dim3(256), 0, stream>>>(
      x, Wq, Wk, Wv, bq, bk, bv, xb, WTall, bcat, Dsum);
  // 2. fused QKV projection: 8-phase 256x256 pipelined GEMM
  gemm8p_qkv<<<dim3(768), dim3(512), 0, stream>>>(xb, WTall, qkv, bcat);
  // 3. P' = exp(scale * q k^T) masked, bf16; Dsum[b][s] = sum_t P'[t][s]
  gemm_p<1><<<dim3(4, 2, B_DIM), dim3(512), 0, stream>>>(
      qkv, qkv + 512, P, nullptr, Dsum, 1536, 1536, T_DIM, sQKV, sQKV, bstr, scale);
  // 4. vT[b][v][s] = v[b][s][v] / Dsum[b][s]
  vtr_kernel<<<dim3(8, 8, B_DIM), dim3(64, 8), 0, stream>>>(qkv + 1024, Dsum, vT, 1536);
  // 5. out = P' @ vT^T (causal K-truncation), f32
  gemm_p<2><<<dim3(4, 2, B_DIM), dim3(512), 0, stream>>>(
      P, vT, out, nullptr, nullptr, 512, 512, T_DIM, bstr, bstr, bstr, 1.f);
}

// Round 7
// 261.218 us; speedup vs baseline: 1.3883x; 1.0472x over previous
//
#include <hip/hip_runtime.h>
#include <hip/hip_bf16.h>
#include <math.h>

#define B_DIM 64
#define T_DIM 512
#define E_DIM 512   // K = V = 512 too

typedef __bf16 bf16_t;
typedef bf16_t bf16x8 __attribute__((ext_vector_type(8)));
typedef bf16_t bf16x4 __attribute__((ext_vector_type(4)));
typedef float  f32x4  __attribute__((ext_vector_type(4)));

typedef unsigned char __attribute__((address_space(1))) uc_g;
typedef unsigned char __attribute__((address_space(3))) uc_l;

__device__ __forceinline__ void gl_lds16(const void* g, void* l) {
  __builtin_amdgcn_global_load_lds((const uc_g*)g, (uc_l*)l, 16, 0, 0);
}

// ============== fused prep: x->bf16 | 3x W transpose->bf16 | bias concat ===========
// grid: [0,8192) cvtx | [8192,8960) wtr | 8960 bcat
__global__ __launch_bounds__(256)
void prep_kernel(const float* __restrict__ x,
                 const float* __restrict__ Wq, const float* __restrict__ Wk,
                 const float* __restrict__ Wv,
                 const float* __restrict__ bq, const float* __restrict__ bk,
                 const float* __restrict__ bv,
                 bf16_t* __restrict__ xb, bf16_t* __restrict__ WTall,
                 float* __restrict__ bcat) {
  __shared__ float tile[32][33];
  const int bx = blockIdx.x;
  const int t = threadIdx.x;
  if (bx < 8192) {                    // ---- x -> bf16, 8 elems/thread
    const size_t i = (size_t)bx * 256 + t;
    const float4 a = ((const float4*)x)[i * 2];
    const float4 b = ((const float4*)x)[i * 2 + 1];
    bf16x8 o;
    o[0] = (bf16_t)a.x; o[1] = (bf16_t)a.y; o[2] = (bf16_t)a.z; o[3] = (bf16_t)a.w;
    o[4] = (bf16_t)b.x; o[5] = (bf16_t)b.y; o[6] = (bf16_t)b.z; o[7] = (bf16_t)b.w;
    *(bf16x8*)(xb + i * 8) = o;
  } else if (bx < 8960) {             // ---- W (E x N) -> WT rows (N x E), bf16
    const int bid = bx - 8192;        // 0..767
    const int z = bid >> 8;           // which weight
    const int tl = bid & 255;
    const int c0 = (tl & 15) * 32, r0 = (tl >> 4) * 32;
    const float* W = z == 0 ? Wq : (z == 1 ? Wk : Wv);
    bf16_t* O = WTall + (size_t)z * 512 * E_DIM;
    const int tx = t & 31, ty = t >> 5;
#pragma unroll
    for (int i = 0; i < 4; ++i)
      tile[ty + i * 8][tx] = W[(size_t)(r0 + ty + i * 8) * E_DIM + c0 + tx];
    __syncthreads();
#pragma unroll
    for (int i = 0; i < 4; ++i)
      O[(size_t)(c0 + ty + i * 8) * E_DIM + r0 + tx] = (bf16_t)tile[tx][ty + i * 8];
  } else {                            // ---- bias concat [1536]
#pragma unroll
    for (int i = t; i < 1536; i += 256)
      bcat[i] = i < 512 ? bq[i] : (i < 1024 ? bk[i - 512] : bv[i - 1024]);
  }
}

// ============== projection: 128x256 tile, BK=32, ring-3 (round-5 verified) =========
// A [32768][512] x WTall [1536][512]^T. bn 0..3 -> q,k into qkv (+bias, bf16).
// bn 4,5 -> v written TRANSPOSED per batch into vT[b][vcol][s] (+bias), so PV can
// consume it directly and the vtr pass is eliminated.
__global__ __launch_bounds__(512)
void proj_kernel(const bf16_t* __restrict__ A, const bf16_t* __restrict__ Bt,
                 bf16_t* __restrict__ qkv, bf16_t* __restrict__ vT,
                 const float* __restrict__ bias) {
  __shared__ bf16_t lds[3][12288];   // [buf][A 128x32 | B 256x32] = 72 KiB
  const int tid = threadIdx.x;

  const int lin = blockIdx.x;                    // 1536 blocks
  const int nl = (lin & 7) * 192 + (lin >> 3);   // chunked XCD swizzle
  const int bm = nl / 6, bn = nl - bm * 6;       // bn-fastest: A-tile L2-reuse x6

  const bf16_t* Ab = A + (long)bm * 128 * 512;
  const bf16_t* Bb = Bt + (long)bn * 256 * 512;

  const int strow = tid >> 2, stg = tid & 3;
  const int sgg = stg ^ ((strow >> 1) & 3);
  const bf16_t* gA  = Ab + (long)strow * 512 + sgg * 8;
  const bf16_t* gB0 = Bb + (long)strow * 512 + sgg * 8;
  const bf16_t* gB1 = gB0 + (long)128 * 512;

#define STAGE(kt, buf) { gl_lds16(gA  + (long)(kt) * 32, &lds[buf][tid * 8]);        \
                         gl_lds16(gB0 + (long)(kt) * 32, &lds[buf][4096 + tid * 8]); \
                         gl_lds16(gB1 + (long)(kt) * 32, &lds[buf][8192 + tid * 8]); }

  const int l15 = tid & 15, lk = (tid >> 4) & 3;
  const int w = tid >> 6, wr = w >> 2, wc = w & 3;
  int aoff[4], boff[4];
#pragma unroll
  for (int m = 0; m < 4; ++m) {
    const int row = wr * 64 + m * 16 + l15;
    aoff[m] = row * 32 + (lk ^ ((row >> 1) & 3)) * 8;
  }
#pragma unroll
  for (int n = 0; n < 4; ++n) {
    const int row = wc * 64 + n * 16 + l15;
    boff[n] = 4096 + row * 32 + (lk ^ ((row >> 1) & 3)) * 8;
  }

  f32x4 acc[4][4] = {};

  STAGE(0, 0); STAGE(1, 1);
  asm volatile("s_waitcnt vmcnt(3)" ::: "memory");
  asm volatile("s_barrier" ::: "memory");

  int cb = 0;
  for (int kt = 0; kt < 16; ++kt) {
    bf16x8 af[4], bfr[4];
#pragma unroll
    for (int m = 0; m < 4; ++m) af[m] = *(const bf16x8*)&lds[cb][aoff[m]];
#pragma unroll
    for (int n = 0; n < 4; ++n) bfr[n] = *(const bf16x8*)&lds[cb][boff[n]];
    const int sb = (cb == 0) ? 2 : cb - 1;
    if (kt + 2 < 16) {
      STAGE(kt + 2, sb);
      asm volatile("s_waitcnt vmcnt(3)" ::: "memory");
    } else if (kt + 2 == 16) {
      asm volatile("s_waitcnt vmcnt(0)" ::: "memory");
    }
    asm volatile("s_barrier" ::: "memory");
    __builtin_amdgcn_s_setprio(1);
#pragma unroll
    for (int m = 0; m < 4; ++m)
#pragma unroll
      for (int n = 0; n < 4; ++n)
        acc[m][n] = __builtin_amdgcn_mfma_f32_16x16x32_bf16(af[m], bfr[n], acc[m][n], 0, 0, 0);
    __builtin_amdgcn_s_setprio(0);
    asm volatile("s_barrier" ::: "memory");
    cb = (cb == 2) ? 0 : cb + 1;
  }
#undef STAGE

  if (bn < 4) {   // ---- q,k: normal row-major store into qkv ----------------------
#pragma unroll
    for (int m = 0; m < 4; ++m) {
      const long row0 = (long)bm * 128 + wr * 64 + m * 16 + lk * 4;
#pragma unroll
      for (int n = 0; n < 4; ++n) {
        const int col = bn * 256 + wc * 64 + n * 16 + l15;
        const float bv = bias[col];
#pragma unroll
        for (int r = 0; r < 4; ++r)
          qkv[(row0 + r) * 1536L + col] = (bf16_t)(acc[m][n][r] + bv);
      }
    }
  } else {        // ---- v: transposed store vT[b][vcol][s] (s = 4 contiguous) ------
#pragma unroll
    for (int m = 0; m < 4; ++m) {
      const long row0 = (long)bm * 128 + wr * 64 + m * 16 + lk * 4;
      const long b = row0 >> 9;
      const int s0 = (int)(row0 & 511);
#pragma unroll
      for (int n = 0; n < 4; ++n) {
        const int col = bn * 256 + wc * 64 + n * 16 + l15;   // 1024..1535
        const float bv = bias[col];
        const int vc = col - 1024;
        bf16x4 o;
#pragma unroll
        for (int r = 0; r < 4; ++r) o[r] = (bf16_t)(acc[m][n][r] + bv);
        *(bf16x4*)(vT + b * 262144 + (long)vc * 512 + s0) = o;
      }
    }
  }
}

// ============== scores column-panel: M=512 (all t) x N=128 (s-tile), K=512 =========
// Per block: full score column panel -> in-block column softmax (axis=t) -> P'norm.
// 8 waves = 4 wr (t 128-chunks) x 2 wc (s 64-chunks); per-wave 128x64, acc[8][4].
// Causal: wave fully masked iff wr < bn (skip MFMA/store, keep barriers).
// D[s] = sum_t e (f32, in-block, LDS atomics); P'norm = bf16(e * invD).
__global__ __launch_bounds__(512)
void scores_kernel(const bf16_t* __restrict__ qkv, bf16_t* __restrict__ P,
                   float scale) {
  __shared__ bf16_t lds[3][20480];   // [buf][A 512x32 | B 128x32] = 120 KiB
  const int tid = threadIdx.x;
  const int bn = blockIdx.x;         // s-block (128 wide), 0..3
  const int bz = blockIdx.y;         // batch
  const bf16_t* q = qkv + (long)bz * T_DIM * 1536;
  const bf16_t* k = q + 512;

  const int strow = tid >> 2, stg = tid & 3;       // strow 0..127
  const int sg = stg ^ ((strow >> 1) & 3);         // pre-swizzled source granule
  const bf16_t* gA = q + (long)strow * 1536 + sg * 8;
  const bf16_t* gB = k + ((long)bn * 128 + strow) * 1536 + sg * 8;

#define STAGE(kt, buf) {                                                            \
    _Pragma("unroll") for (int i_ = 0; i_ < 4; ++i_)                                \
      gl_lds16(gA + (long)(kt) * 32 + (long)i_ * 128 * 1536,                        \
               &lds[buf][i_ * 4096 + tid * 8]);                                     \
    gl_lds16(gB + (long)(kt) * 32, &lds[buf][16384 + tid * 8]); }

  const int l15 = tid & 15, lk = (tid >> 4) & 3;
  const int w = tid >> 6, wr = w >> 1, wc = w & 1;   // 4 x 2 wave grid
  const int active = (wr >= bn);
  int aoffs[8], boffs[4];
#pragma unroll
  for (int mm = 0; mm < 8; ++mm) {
    const int row = wr * 128 + mm * 16 + l15;
    aoffs[mm] = row * 32 + (lk ^ ((row >> 1) & 3)) * 8;
  }
#pragma unroll
  for (int n = 0; n < 4; ++n) {
    const int row = wc * 64 + n * 16 + l15;
    boffs[n] = 16384 + row * 32 + (lk ^ ((row >> 1) & 3)) * 8;
  }

  f32x4 acc[8][4] = {};

  STAGE(0, 0); STAGE(1, 1);
  asm volatile("s_waitcnt vmcnt(5)" ::: "memory");   // tile 0 landed (5 of tile 1 fly)
  asm volatile("s_barrier" ::: "memory");

  int cb = 0;
  for (int kt = 0; kt < 16; ++kt) {
    bf16x8 af[8], bfr[4];
    if (active) {
#pragma unroll
      for (int mm = 0; mm < 8; ++mm) af[mm] = *(const bf16x8*)&lds[cb][aoffs[mm]];
#pragma unroll
      for (int n = 0; n < 4; ++n) bfr[n] = *(const bf16x8*)&lds[cb][boffs[n]];
    }
    const int sb = (cb == 0) ? 2 : cb - 1;
    if (kt + 2 < 16) {
      STAGE(kt + 2, sb);
      asm volatile("s_waitcnt vmcnt(5)" ::: "memory");
    } else if (kt + 2 == 16) {
      asm volatile("s_waitcnt vmcnt(0)" ::: "memory");
    }
    asm volatile("s_barrier" ::: "memory");
    if (active) {
      __builtin_amdgcn_s_setprio(1);
#pragma unroll
      for (int mm = 0; mm < 8; ++mm)
#pragma unroll
        for (int n = 0; n < 4; ++n)
          acc[mm][n] = __builtin_amdgcn_mfma_f32_16x16x32_bf16(af[mm], bfr[n], acc[mm][n], 0, 0, 0);
      __builtin_amdgcn_s_setprio(0);
    }
    asm volatile("s_barrier" ::: "memory");
    cb = (cb == 2) ? 0 : cb + 1;
  }
#undef STAGE

  // ---- in-block column softmax (no max-sub: |score| < ~8 statistically) ----------
  float* colsum = (float*)&lds[0][0];   // 128 floats; ring LDS dead
  if (tid < 128) colsum[tid] = 0.f;
  __syncthreads();

  float ts[4] = {0.f, 0.f, 0.f, 0.f};
  if (active) {
#pragma unroll
    for (int mm = 0; mm < 8; ++mm) {
      const int trow = wr * 128 + mm * 16 + lk * 4;
#pragma unroll
      for (int n = 0; n < 4; ++n) {
        const int scol = bn * 128 + wc * 64 + n * 16 + l15;
#pragma unroll
        for (int r = 0; r < 4; ++r) {
          float e = 0.f;
          if (scol <= trow + r) e = __expf(acc[mm][n][r] * scale);
          acc[mm][n][r] = e;
          ts[n] += e;
        }
      }
    }
#pragma unroll
    for (int n = 0; n < 4; ++n) {   // reduce over lk groups (same column set)
      ts[n] += __shfl_xor(ts[n], 16);
      ts[n] += __shfl_xor(ts[n], 32);
    }
    if (lk == 0) {
#pragma unroll
      for (int n = 0; n < 4; ++n)
        atomicAdd(&colsum[wc * 64 + n * 16 + l15], ts[n]);
    }
  }
  __syncthreads();

  if (active) {
    bf16_t* Pb = P + (long)bz * 262144;
    float inv[4];
#pragma unroll
    for (int n = 0; n < 4; ++n)
      inv[n] = 1.0f / colsum[wc * 64 + n * 16 + l15];
#pragma unroll
    for (int mm = 0; mm < 8; ++mm) {
      const int trow = wr * 128 + mm * 16 + lk * 4;
#pragma unroll
      for (int n = 0; n < 4; ++n) {
        const int scol = bn * 128 + wc * 64 + n * 16 + l15;
#pragma unroll
        for (int r = 0; r < 4; ++r)
          Pb[(long)(trow + r) * 512 + scol] = (bf16_t)(acc[mm][n][r] * inv[n]);
      }
    }
  }
}

// ============== PV: 128x256 tile, BK=32, ring-3, causal K-truncation ==============
// out[t][v] = sum_s P'norm[t][s] * vT[v][s]  (NT form), f32 store.
__global__ __launch_bounds__(512)
void pv_kernel(const bf16_t* __restrict__ Pn, const bf16_t* __restrict__ vT,
               float* __restrict__ out) {
  __shared__ bf16_t lds[3][12288];   // 72 KiB
  const int tid = threadIdx.x;
  const int bm = blockIdx.x, bn = blockIdx.y, bz = blockIdx.z;
  const int NT = (bm + 1) * 4;       // s < (bm+1)*128

  const bf16_t* Ab = Pn + (long)bz * 262144 + (long)bm * 128 * 512;
  const bf16_t* Bb = vT + (long)bz * 262144 + (long)bn * 256 * 512;

  const int strow = tid >> 2, stg = tid & 3;
  const int sgg = stg ^ ((strow >> 1) & 3);
  const bf16_t* gA  = Ab + (long)strow * 512 + sgg * 8;
  const bf16_t* gB0 = Bb + (long)strow * 512 + sgg * 8;
  const bf16_t* gB1 = gB0 + (long)128 * 512;

#define STAGE(kt, buf) { gl_lds16(gA  + (long)(kt) * 32, &lds[buf][tid * 8]);        \
                         gl_lds16(gB0 + (long)(kt) * 32, &lds[buf][4096 + tid * 8]); \
                         gl_lds16(gB1 + (long)(kt) * 32, &lds[buf][8192 + tid * 8]); }

  const int l15 = tid & 15, lk = (tid >> 4) & 3;
  const int w = tid >> 6, wr = w >> 2, wc = w & 3;
  int aoff[4], boff[4];
#pragma unroll
  for (int m = 0; m < 4; ++m) {
    const int row = wr * 64 + m * 16 + l15;
    aoff[m] = row * 32 + (lk ^ ((row >> 1) & 3)) * 8;
  }
#pragma unroll
  for (int n = 0; n < 4; ++n) {
    const int row = wc * 64 + n * 16 + l15;
    boff[n] = 4096 + row * 32 + (lk ^ ((row >> 1) & 3)) * 8;
  }

  f32x4 acc[4][4] = {};

  STAGE(0, 0);
  if (NT > 1) STAGE(1, 1);
  asm volatile("s_waitcnt vmcnt(3)" ::: "memory");
  asm volatile("s_barrier" ::: "memory");

  int cb = 0;
  for (int kt = 0; kt < NT; ++kt) {
    bf16x8 af[4], bfr[4];
#pragma unroll
    for (int m = 0; m < 4; ++m) af[m] = *(const bf16x8*)&lds[cb][aoff[m]];
#pragma unroll
    for (int n = 0; n < 4; ++n) bfr[n] = *(const bf16x8*)&lds[cb][boff[n]];
    const int sb = (cb == 0) ? 2 : cb - 1;
    if (kt + 2 < NT) {
      STAGE(kt + 2, sb);
      asm volatile("s_waitcnt vmcnt(3)" ::: "memory");
    } else if (kt + 2 == NT) {
      asm volatile("s_waitcnt vmcnt(0)" ::: "memory");
    }
    asm volatile("s_barrier" ::: "memory");
    __builtin_amdgcn_s_setprio(1);
#pragma unroll
    for (int m = 0; m < 4; ++m)
#pragma unroll
      for (int n = 0; n < 4; ++n)
        acc[m][n] = __builtin_amdgcn_mfma_f32_16x16x32_bf16(af[m], bfr[n], acc[m][n], 0, 0, 0);
    __builtin_amdgcn_s_setprio(0);
    asm volatile("s_barrier" ::: "memory");
    cb = (cb == 2) ? 0 : cb + 1;
  }
#undef STAGE

  float* C = out + (long)bz * 262144;
#pragma unroll
  for (int m = 0; m < 4; ++m) {
    const long row0 = (long)bm * 128 + wr * 64 + m * 16 + lk * 4;
#pragma unroll
    for (int n = 0; n < 4; ++n) {
      const int col = bn * 256 + wc * 64 + n * 16 + l15;
#pragma unroll
      for (int r = 0; r < 4; ++r)
        C[(row0 + r) * 512 + col] = acc[m][n][r];
    }
  }
}

// ----------------------------------------------------------------------------------
extern "C" void kernel_launch(void* const* d_in, const int* in_sizes, int n_in,
                              void* d_out, int out_size, void* d_ws, size_t ws_size,
                              hipStream_t stream) {
  const float* x  = (const float*)d_in[0];
  const float* Wq = (const float*)d_in[1];
  const float* bq = (const float*)d_in[2];
  const float* Wk = (const float*)d_in[3];
  const float* bk = (const float*)d_in[4];
  const float* Wv = (const float*)d_in[5];
  const float* bv = (const float*)d_in[6];
  float* out = (float*)d_out;

  char* ws = (char*)d_ws;
  const size_t SZ = (size_t)B_DIM * T_DIM * E_DIM * 2;      // 33,554,432 B
  bf16_t* xb    = (bf16_t*)(ws);                            // dead after projection
  bf16_t* P     = (bf16_t*)(ws);                            // P'norm overlays xb
  bf16_t* qkv   = (bf16_t*)(ws + SZ);                       // [32768][1536] (q,k thirds)
  bf16_t* vT    = (bf16_t*)(ws + 4 * SZ);                   // [B][512 vcol][512 s]
  bf16_t* WTall = (bf16_t*)(ws + 5 * SZ);                   // [1536][512]
  float*  bcat  = (float*)(ws + 5 * SZ + 1572864);          // [1536]

  const float scale = 1.0f / sqrtf((float)E_DIM);

  // 1. fused prep: x->bf16, W transposes, bias concat
  prep_kernel<<<dim3(8961), dim3(256), 0, stream>>>(
      x, Wq, Wk, Wv, bq, bk, bv, xb, WTall, bcat);
  // 2. projection: q,k -> qkv; v -> vT (transposed, +bias)
  proj_kernel<<<dim3(1536), dim3(512), 0, stream>>>(xb, WTall, qkv, vT, bcat);
  // 3. scores column panel + in-block column softmax -> P'norm
  scores_kernel<<<dim3(4, B_DIM), dim3(512), 0, stream>>>(qkv, P, scale);
  // 4. out = P'norm @ vT^T (causal K-truncation), f32
  pv_kernel<<<dim3(4, 2, B_DIM), dim3(512), 0, stream>>>(P, vT, out);
}